// Round 11
// baseline (1164.433 us; speedup 1.0000x reference)
//
#include <hip/hip_runtime.h>
#include <stdint.h>

static constexpr int kB = 8, kS = 2048, kD = 1024, kF = 4096, kE = 8, kC = 512;

typedef unsigned short u16;
typedef __attribute__((ext_vector_type(8))) short bf16x8;
typedef __attribute__((ext_vector_type(4))) float f32x4;

__device__ __forceinline__ u16 f2bf(float f) {
    union { float f; uint32_t u; } v; v.f = f;
    return (u16)((v.u + 0x7fffu + ((v.u >> 16) & 1u)) >> 16);
}
__device__ __forceinline__ void gload16(const u16* g, u16* l) {
    __builtin_amdgcn_global_load_lds(
        (__attribute__((address_space(1))) void*)(u16*)g,
        (__attribute__((address_space(3))) void*)l, 16, 0, 0);
}

// tile decode: bid -> (pem, mt, nt, pl). swz groups same-(pair,mt) nt-sharers on one XCD.
__device__ __forceinline__ void decode_tile(int bid, int NT, int p0em, int swz,
                                            int& pem, int& mt, int& nt, int& pl) {
    int g;
    if (swz) {
        int xcd = bid & 7;
        int lin = bid >> 3;
        nt = lin % NT;
        g = (lin / NT) * 8 + xcd;
    } else {
        g = bid / NT;
        nt = bid % NT;
    }
    pl = g >> 2;
    mt = g & 3;
    pem = p0em + pl;          // expert-major index: pem = e*8 + b
}

// ---------------- init: zero the fp32 `out` region of d_out ----------------
__global__ void init_k(uint4* __restrict__ outz) {
    const size_t n = (size_t)kB * kS * kD * 4 / 16;
    size_t stride = (size_t)gridDim.x * blockDim.x;
    for (size_t i = (size_t)blockIdx.x * blockDim.x + threadIdx.x; i < n; i += stride)
        outz[i] = (uint4){0, 0, 0, 0};
}

// ---------------- hidden fp32 -> bf16 image; block 0 also zeroes the zero page ----------------
__global__ void conv_hidden_k(const float* __restrict__ src, u16* __restrict__ hbf,
                              uint4* __restrict__ zerobuf) {
    if (blockIdx.x == 0 && threadIdx.x < 144) zerobuf[threadIdx.x] = (uint4){0, 0, 0, 0};
    const size_t n = (size_t)kB * kS * kD;
    size_t i0 = ((size_t)blockIdx.x * blockDim.x + threadIdx.x) * 8;
    size_t stride = (size_t)gridDim.x * blockDim.x * 8;
    for (size_t i = i0; i < n; i += stride) {
        float4 a = *(const float4*)(src + i);
        float4 b = *(const float4*)(src + i + 4);
        u16 t[8] = {f2bf(a.x), f2bf(a.y), f2bf(a.z), f2bf(a.w),
                    f2bf(b.x), f2bf(b.y), f2bf(b.z), f2bf(b.w)};
        *(uint4*)(hbf + i) = *(const uint4*)t;
    }
}

// ---------------- router: fp32 logits, softmax, first-wins argmax (proven) ----------
__global__ __launch_bounds__(256) void router_k(
    const float* __restrict__ hidden, const float* __restrict__ rw,
    float* __restrict__ logits_out, int* __restrict__ expert_id, float* __restrict__ maxprob)
{
    int token = blockIdx.x * 4 + (threadIdx.x >> 6);
    int lane = threadIdx.x & 63;
    const float* hrow = hidden + (size_t)token * kD;
    float acc[8] = {0, 0, 0, 0, 0, 0, 0, 0};
    for (int d0 = lane * 4; d0 < kD; d0 += 256) {
        float4 h4 = *(const float4*)(hrow + d0);
        float hv[4] = {h4.x, h4.y, h4.z, h4.w};
        #pragma unroll
        for (int j = 0; j < 4; j++) {
            const float* wr = rw + (size_t)(d0 + j) * 8;
            float4 w0 = *(const float4*)wr, w1 = *(const float4*)(wr + 4);
            acc[0] += hv[j] * w0.x; acc[1] += hv[j] * w0.y;
            acc[2] += hv[j] * w0.z; acc[3] += hv[j] * w0.w;
            acc[4] += hv[j] * w1.x; acc[5] += hv[j] * w1.y;
            acc[6] += hv[j] * w1.z; acc[7] += hv[j] * w1.w;
        }
    }
    #pragma unroll
    for (int off = 32; off >= 1; off >>= 1) {
        #pragma unroll
        for (int e = 0; e < 8; e++) acc[e] += __shfl_down(acc[e], off, 64);
    }
    if (lane == 0) {
        float m = acc[0];
        #pragma unroll
        for (int e = 1; e < 8; e++) m = fmaxf(m, acc[e]);
        float ex[8], s = 0.f;
        #pragma unroll
        for (int e = 0; e < 8; e++) { ex[e] = expf(acc[e] - m); s += ex[e]; }
        int best = 0; float bv = -1.f;
        #pragma unroll
        for (int e = 0; e < 8; e++) {
            float p = ex[e] / s;
            if (p > bv) { bv = p; best = e; }
            logits_out[(size_t)token * 8 + e] = acc[e];
        }
        expert_id[token] = best;
        maxprob[token] = bv;
    }
}

// ---------------- capacity scan (proven) ----------------
__global__ __launch_bounds__(64) void scan_k(
    const int* __restrict__ expert_id, int* __restrict__ slot_token,
    int* __restrict__ counts, float* __restrict__ expidx_out)
{
    __shared__ int eids[kS];
    int b = blockIdx.x, tid = threadIdx.x;
    for (int s = tid; s < kS; s += 64) eids[s] = expert_id[b * kS + s];
    __syncthreads();
    if (tid < kE) {
        int e = tid, cnt = 0;
        for (int s = 0; s < kS; s++) {
            if (eids[s] == e) {
                if (cnt < kC) {
                    slot_token[(b * kE + e) * kC + cnt] = s;
                    expidx_out[b * kS + s] = (float)e;
                    cnt++;
                } else {
                    expidx_out[b * kS + s] = 0.f;
                }
            }
        }
        counts[b * kE + e] = cnt;
        for (int c = cnt; c < kC; c++) slot_token[(b * kE + e) * kC + c] = -1;
    }
}

// ---------------- transpose fp32 [R][Cn] -> bf16 [Cn][R]; blockIdx.z = expert ----------------
__global__ void transpose_k(const float* __restrict__ src, u16* __restrict__ dst, int R, int Cn) {
    __shared__ u16 t[32][33];
    size_t eo = (size_t)blockIdx.z * R * Cn;
    int c0 = blockIdx.x * 32, r0 = blockIdx.y * 32;
    int tx = threadIdx.x, ty = threadIdx.y;
    #pragma unroll
    for (int i = 0; i < 4; i++)
        t[ty + i * 8][tx] = f2bf(src[eo + (size_t)(r0 + ty + i * 8) * Cn + c0 + tx]);
    __syncthreads();
    #pragma unroll
    for (int i = 0; i < 4; i++)
        dst[eo + (size_t)(c0 + ty + i * 8) * R + r0 + tx] = t[tx][ty + i * 8];
}

// ---------------- MFMA GEMM1: H = relu(gather(hbf) @ wi), bf16 H; dbuf K-loop ----------------
__global__ __launch_bounds__(256) void gemm1_k(
    const u16* __restrict__ hbf, const u16* __restrict__ wiT, size_t wstride,
    const int* __restrict__ slot_token, const int* __restrict__ counts,
    const u16* __restrict__ zerobuf, u16* __restrict__ Hbuf, int p0em, int swz)
{
    constexpr int NT = kF / 128;  // 32
    constexpr int NK = kD / 32;   // 32 K-steps
    int pem, mt, nt, pl;
    decode_tile(blockIdx.x, NT, p0em, swz, pem, mt, nt, pl);
    int e = pem >> 3, b = pem & 7;
    int pair = b * kE + e;
    const u16* wbase = wiT + (size_t)e * wstride;
    int cnt = counts[pair];
    if (mt * 128 >= cnt) return;

    __shared__ __align__(16) u16 As[2][128 * 32];
    __shared__ __align__(16) u16 Bs[2][128 * 32];
    __shared__ int slots[128];
    int tid = threadIdx.x, wave = tid >> 6, lane = tid & 63;
    if (tid < 128) slots[tid] = slot_token[pair * kC + mt * 128 + tid];
    __syncthreads();

    int wr = wave >> 1, wc = wave & 1;
    int fr = lane & 15, fq = lane >> 4;
    int srow = lane >> 2, kb = (lane & 3) * 8;
    int sl0 = slots[(wave)     * 16 + srow];
    int sl1 = slots[(wave + 4) * 16 + srow];
    const u16* a0 = (sl0 >= 0) ? hbf + (size_t)(b * kS + sl0) * kD + kb : zerobuf + kb;
    const u16* a1 = (sl1 >= 0) ? hbf + (size_t)(b * kS + sl1) * kD + kb : zerobuf + kb;
    const u16* b0 = wbase + ((size_t)(nt * 128 + wave * 16 + srow)) * kD + kb;
    const u16* b1 = wbase + ((size_t)(nt * 128 + (wave + 4) * 16 + srow)) * kD + kb;

    auto stage = [&](int buf, int k0) {
        gload16(a0 + k0, As[buf] + (wave)     * 512);
        gload16(a1 + k0, As[buf] + (wave + 4) * 512);
        gload16(b0 + k0, Bs[buf] + (wave)     * 512);
        gload16(b1 + k0, Bs[buf] + (wave + 4) * 512);
    };

    f32x4 acc[4][4];
    #pragma unroll
    for (int m = 0; m < 4; m++)
        #pragma unroll
        for (int n = 0; n < 4; n++) acc[m][n] = (f32x4){0.f, 0.f, 0.f, 0.f};

    stage(0, 0);
    __syncthreads();

    #pragma unroll 1
    for (int t = 0; t < NK; t++) {
        int cur = t & 1;
        if (t + 1 < NK) stage(cur ^ 1, (t + 1) * 32);
        const u16* Ac = As[cur];
        const u16* Bc = Bs[cur];
        bf16x8 af[4], bfr[4];
        #pragma unroll
        for (int m = 0; m < 4; m++)
            af[m] = *(const bf16x8*)(Ac + (wr * 64 + m * 16 + fr) * 32 + fq * 8);
        #pragma unroll
        for (int n = 0; n < 4; n++)
            bfr[n] = *(const bf16x8*)(Bc + (wc * 64 + n * 16 + fr) * 32 + fq * 8);
        #pragma unroll
        for (int m = 0; m < 4; m++)
            #pragma unroll
            for (int n = 0; n < 4; n++)
                acc[m][n] = __builtin_amdgcn_mfma_f32_16x16x32_bf16(af[m], bfr[n], acc[m][n], 0, 0, 0);
        __syncthreads();
    }

    size_t hbase = (size_t)pl * kC * kF;
    int r0 = mt * 128 + wr * 64, c0 = nt * 128 + wc * 64;
    #pragma unroll
    for (int m = 0; m < 4; m++) {
        #pragma unroll
        for (int j = 0; j < 4; j++) {
            int row = r0 + m * 16 + fq * 4 + j;
            size_t rb = hbase + (size_t)row * kF;
            #pragma unroll
            for (int n = 0; n < 4; n++) {
                int col = c0 + n * 16 + fr;
                Hbuf[rb + col] = f2bf(fmaxf(acc[m][n][j], 0.f));
            }
        }
    }
}

// ---------------- MFMA GEMM2: out = (H @ wo) * max_prob; dbuf K-loop ----------------
__global__ __launch_bounds__(256) void gemm2_k(
    const u16* __restrict__ Hbuf, const u16* __restrict__ woT, size_t wstride,
    const int* __restrict__ slot_token, const int* __restrict__ counts,
    const float* __restrict__ maxprob, float* __restrict__ outp, int p0em, int swz)
{
    constexpr int NT = kD / 128;  // 8
    constexpr int NK = kF / 32;   // 128 K-steps
    int pem, mt, nt, pl;
    decode_tile(blockIdx.x, NT, p0em, swz, pem, mt, nt, pl);
    int e = pem >> 3, b = pem & 7;
    int pair = b * kE + e;
    const u16* wbase = woT + (size_t)e * wstride;
    int cnt = counts[pair];
    if (mt * 128 >= cnt) return;

    __shared__ __align__(16) u16 As[2][128 * 32];
    __shared__ __align__(16) u16 Bs[2][128 * 32];
    __shared__ int slots[128];
    int tid = threadIdx.x, wave = tid >> 6, lane = tid & 63;
    if (tid < 128) slots[tid] = slot_token[pair * kC + mt * 128 + tid];
    __syncthreads();

    int wr = wave >> 1, wc = wave & 1;
    int fr = lane & 15, fq = lane >> 4;
    int srow = lane >> 2, kb = (lane & 3) * 8;
    const u16* a0 = Hbuf + ((size_t)pl * kC + mt * 128 + wave * 16 + srow) * kF + kb;
    const u16* a1 = Hbuf + ((size_t)pl * kC + mt * 128 + (wave + 4) * 16 + srow) * kF + kb;
    const u16* b0 = wbase + ((size_t)(nt * 128 + wave * 16 + srow)) * kF + kb;
    const u16* b1 = wbase + ((size_t)(nt * 128 + (wave + 4) * 16 + srow)) * kF + kb;

    auto stage = [&](int buf, int k0) {
        gload16(a0 + k0, As[buf] + (wave)     * 512);
        gload16(a1 + k0, As[buf] + (wave + 4) * 512);
        gload16(b0 + k0, Bs[buf] + (wave)     * 512);
        gload16(b1 + k0, Bs[buf] + (wave + 4) * 512);
    };

    f32x4 acc[4][4];
    #pragma unroll
    for (int m = 0; m < 4; m++)
        #pragma unroll
        for (int n = 0; n < 4; n++) acc[m][n] = (f32x4){0.f, 0.f, 0.f, 0.f};

    stage(0, 0);
    __syncthreads();

    #pragma unroll 1
    for (int t = 0; t < NK; t++) {
        int cur = t & 1;
        if (t + 1 < NK) stage(cur ^ 1, (t + 1) * 32);
        const u16* Ac = As[cur];
        const u16* Bc = Bs[cur];
        bf16x8 af[4], bfr[4];
        #pragma unroll
        for (int m = 0; m < 4; m++)
            af[m] = *(const bf16x8*)(Ac + (wr * 64 + m * 16 + fr) * 32 + fq * 8);
        #pragma unroll
        for (int n = 0; n < 4; n++)
            bfr[n] = *(const bf16x8*)(Bc + (wc * 64 + n * 16 + fr) * 32 + fq * 8);
        #pragma unroll
        for (int m = 0; m < 4; m++)
            #pragma unroll
            for (int n = 0; n < 4; n++)
                acc[m][n] = __builtin_amdgcn_mfma_f32_16x16x32_bf16(af[m], bfr[n], acc[m][n], 0, 0, 0);
        __syncthreads();
    }

    int c0 = nt * 128 + wc * 64;
    #pragma unroll
    for (int m = 0; m < 4; m++) {
        #pragma unroll
        for (int j = 0; j < 4; j++) {
            int rlocal = wr * 64 + m * 16 + fq * 4 + j;
            int s = slots[rlocal];
            if (s >= 0) {
                float p = maxprob[b * kS + s];
                size_t ob = (size_t)(b * kS + s) * kD;
                #pragma unroll
                for (int n = 0; n < 4; n++) {
                    int col = c0 + n * 16 + fr;
                    outp[ob + col] = acc[m][n][j] * p;
                }
            }
        }
    }
}

// ---------------- naive fp32 fallback (proven) ----------------
__global__ __launch_bounds__(256) void ngemm1_k(
    const float* __restrict__ hidden, const float* __restrict__ wi,
    const int* __restrict__ slot_token, const int* __restrict__ counts,
    float* __restrict__ H, int pair)
{
    int b = pair >> 3, e = pair & 7;
    int cnt = counts[pair];
    int c0 = blockIdx.y * 64, f0 = blockIdx.x * 64;
    if (c0 >= cnt) return;
    __shared__ float As[64][17];
    __shared__ float Bs[16][65];
    __shared__ int slots[64];
    int tx = threadIdx.x, ty = threadIdx.y;
    int tid = ty * 16 + tx;
    if (tid < 64) slots[tid] = slot_token[pair * kC + c0 + tid];
    __syncthreads();
    float acc[4][4];
    #pragma unroll
    for (int i = 0; i < 4; i++)
        #pragma unroll
        for (int j = 0; j < 4; j++) acc[i][j] = 0.f;
    int ar = tid >> 2, ak = (tid & 3) * 4;
    int bd = tid >> 4, bf = (tid & 15) * 4;
    const float* wie = wi + (size_t)e * kD * kF;
    for (int k0 = 0; k0 < kD; k0 += 16) {
        int sl = slots[ar];
        if (sl >= 0) {
            float4 v = *(const float4*)(hidden + (size_t)(b * kS + sl) * kD + k0 + ak);
            As[ar][ak] = v.x; As[ar][ak + 1] = v.y; As[ar][ak + 2] = v.z; As[ar][ak + 3] = v.w;
        } else {
            As[ar][ak] = 0.f; As[ar][ak + 1] = 0.f; As[ar][ak + 2] = 0.f; As[ar][ak + 3] = 0.f;
        }
        float4 w = *(const float4*)(wie + (size_t)(k0 + bd) * kF + f0 + bf);
        Bs[bd][bf] = w.x; Bs[bd][bf + 1] = w.y; Bs[bd][bf + 2] = w.z; Bs[bd][bf + 3] = w.w;
        __syncthreads();
        #pragma unroll
        for (int kk = 0; kk < 16; kk++) {
            float a[4], bv[4];
            #pragma unroll
            for (int i = 0; i < 4; i++) a[i] = As[ty * 4 + i][kk];
            #pragma unroll
            for (int j = 0; j < 4; j++) bv[j] = Bs[kk][tx * 4 + j];
            #pragma unroll
            for (int i = 0; i < 4; i++)
                #pragma unroll
                for (int j = 0; j < 4; j++) acc[i][j] += a[i] * bv[j];
        }
        __syncthreads();
    }
    #pragma unroll
    for (int i = 0; i < 4; i++) {
        int row = c0 + ty * 4 + i;
        #pragma unroll
        for (int j = 0; j < 4; j++)
            H[(size_t)row * kF + f0 + tx * 4 + j] = fmaxf(acc[i][j], 0.f);
    }
}

__global__ __launch_bounds__(256) void ngemm2_k(
    const float* __restrict__ H, const float* __restrict__ wo,
    const int* __restrict__ slot_token, const int* __restrict__ counts,
    const float* __restrict__ maxprob, float* __restrict__ outp, int pair)
{
    int b = pair >> 3, e = pair & 7;
    int cnt = counts[pair];
    int c0 = blockIdx.y * 64, d0 = blockIdx.x * 64;
    if (c0 >= cnt) return;
    __shared__ float As[64][17];
    __shared__ float Bs[16][65];
    __shared__ int slots[64];
    int tx = threadIdx.x, ty = threadIdx.y;
    int tid = ty * 16 + tx;
    if (tid < 64) slots[tid] = slot_token[pair * kC + c0 + tid];
    __syncthreads();
    float acc[4][4];
    #pragma unroll
    for (int i = 0; i < 4; i++)
        #pragma unroll
        for (int j = 0; j < 4; j++) acc[i][j] = 0.f;
    int ar = tid >> 2, ak = (tid & 3) * 4;
    int bd = tid >> 4, bf = (tid & 15) * 4;
    const float* woe = wo + (size_t)e * kF * kD;
    for (int k0 = 0; k0 < kF; k0 += 16) {
        float4 v = *(const float4*)(H + (size_t)(c0 + ar) * kF + k0 + ak);
        As[ar][ak] = v.x; As[ar][ak + 1] = v.y; As[ar][ak + 2] = v.z; As[ar][ak + 3] = v.w;
        float4 w = *(const float4*)(woe + (size_t)(k0 + bd) * kD + d0 + bf);
        Bs[bd][bf] = w.x; Bs[bd][bf + 1] = w.y; Bs[bd][bf + 2] = w.z; Bs[bd][bf + 3] = w.w;
        __syncthreads();
        #pragma unroll
        for (int kk = 0; kk < 16; kk++) {
            float a[4], bv[4];
            #pragma unroll
            for (int i = 0; i < 4; i++) a[i] = As[ty * 4 + i][kk];
            #pragma unroll
            for (int j = 0; j < 4; j++) bv[j] = Bs[kk][tx * 4 + j];
            #pragma unroll
            for (int i = 0; i < 4; i++)
                #pragma unroll
                for (int j = 0; j < 4; j++) acc[i][j] += a[i] * bv[j];
        }
        __syncthreads();
    }
    #pragma unroll
    for (int i = 0; i < 4; i++) {
        int s = slots[ty * 4 + i];
        if (s >= 0) {
            float p = maxprob[b * kS + s];
            size_t ob = (size_t)(b * kS + s) * kD;
            #pragma unroll
            for (int j = 0; j < 4; j++)
                outp[ob + d0 + tx * 4 + j] = acc[i][j] * p;
        }
    }
}

extern "C" void kernel_launch(void* const* d_in, const int* in_sizes, int n_in,
                              void* d_out, int out_size, void* d_ws, size_t ws_size,
                              hipStream_t stream)
{
    const float* hidden = (const float*)d_in[0];
    const float* rw     = (const float*)d_in[1];
    const float* wi     = (const float*)d_in[2];
    const float* wo     = (const float*)d_in[3];
    float* outp   = (float*)d_out;
    float* logits = outp + (size_t)kB * kS * kD;
    float* expidx = logits + (size_t)kB * kS * kE;

    char* ws = (char*)d_ws;
    size_t off = 0;
    auto alloc = [&](size_t bytes) -> char* {
        char* p = ws + off; off += (bytes + 255) & ~(size_t)255; return p;
    };
    int*   slot_token = (int*)  alloc((size_t)kB * kE * kC * 4);
    int*   counts     = (int*)  alloc((size_t)kB * kE * 4);
    int*   expert_id  = (int*)  alloc((size_t)kB * kS * 4);
    float* maxprob    = (float*)alloc((size_t)kB * kS * 4);
    size_t small_off = off;               // ~1.2 MiB

    const size_t wsz    = (size_t)kD * kF * 2;       // 8 MiB per expert, bf16
    const size_t hsz    = (size_t)kC * kF * 2;       // 4 MiB per pair, bf16
    const size_t hbfsz  = (size_t)kB * kS * kD * 2;  // 32 MiB bf16 hidden image

    init_k<<<2048, 256, 0, stream>>>((uint4*)outp);
    router_k<<<kB * kS / 4, 256, 0, stream>>>(hidden, rw, logits, expert_id, maxprob);
    scan_k<<<kB, 64, 0, stream>>>(expert_id, slot_token, counts, expidx);

    if (ws_size >= small_off + 2 * kE * wsz + hbfsz + 4096 + 4 * hsz) {
        // ---- tier A: all-expert weights; pair-groups capped at 32 so per-dispatch
        //      touched set (<=224 MB) stays L3-resident; XCD swizzle for L2 reuse ----
        u16* wiT = (u16*)alloc(kE * wsz);   // 64 MiB
        u16* woT = (u16*)alloc(kE * wsz);   // 64 MiB
        u16* hbf = (u16*)alloc(hbfsz);      // 32 MiB
        u16* zerobuf = (u16*)alloc(4096);
        int Gb = (int)((ws_size - off) / hsz);
        if (Gb > 32) Gb = 32;               // L3-residency cap (Hbuf <= 128 MiB)
        if (Gb < 1) Gb = 1;
        u16* Hbuf = (u16*)alloc((size_t)Gb * hsz);
        conv_hidden_k<<<2048, 256, 0, stream>>>(hidden, hbf, (uint4*)zerobuf);
        transpose_k<<<dim3(kF / 32, kD / 32, kE), dim3(32, 8), 0, stream>>>(wi, wiT, kD, kF);
        transpose_k<<<dim3(kD / 32, kF / 32, kE), dim3(32, 8), 0, stream>>>(wo, woT, kF, kD);
        for (int p0 = 0; p0 < kB * kE; p0 += Gb) {
            int g = kB * kE - p0 < Gb ? kB * kE - p0 : Gb;
            int swz = ((g * 4) % 8 == 0) ? 1 : 0;
            gemm1_k<<<g * 4 * (kF / 128), 256, 0, stream>>>(
                hbf, wiT, (size_t)kD * kF, slot_token, counts, zerobuf, Hbuf, p0, swz);
            gemm2_k<<<g * 4 * (kD / 128), 256, 0, stream>>>(
                Hbuf, woT, (size_t)kD * kF, slot_token, counts, maxprob, outp, p0, swz);
        }
    } else if (ws_size >= small_off + 2 * wsz + hbfsz + 4096 + hsz) {
        // ---- tier B: per-expert transposed weights ----
        u16* wiT = (u16*)alloc(wsz);
        u16* woT = (u16*)alloc(wsz);
        u16* hbf = (u16*)alloc(hbfsz);
        u16* zerobuf = (u16*)alloc(4096);
        int Gb = (int)((ws_size - off) / hsz);
        if (Gb > kB) Gb = kB;
        if (Gb < 1) Gb = 1;
        u16* Hbuf = (u16*)alloc((size_t)Gb * hsz);
        conv_hidden_k<<<2048, 256, 0, stream>>>(hidden, hbf, (uint4*)zerobuf);
        for (int e = 0; e < kE; e++) {
            transpose_k<<<dim3(kF / 32, kD / 32, 1), dim3(32, 8), 0, stream>>>(
                wi + (size_t)e * kD * kF, wiT, kD, kF);
            transpose_k<<<dim3(kD / 32, kF / 32, 1), dim3(32, 8), 0, stream>>>(
                wo + (size_t)e * kD * kF, woT, kF, kD);
            for (int b0 = 0; b0 < kB; b0 += Gb) {
                int g = kB - b0 < Gb ? kB - b0 : Gb;
                int p0em = e * 8 + b0;   // contiguous in expert-major space
                int swz = ((g * 4) % 8 == 0) ? 1 : 0;
                gemm1_k<<<g * 4 * (kF / 128), 256, 0, stream>>>(
                    hbf, wiT, 0, slot_token, counts, zerobuf, Hbuf, p0em, swz);
                gemm2_k<<<g * 4 * (kD / 128), 256, 0, stream>>>(
                    Hbuf, woT, 0, slot_token, counts, maxprob, outp, p0em, swz);
            }
        }
    } else {
        // ---- tier C: proven naive fp32 fallback ----
        float* H = (float*)alloc((size_t)kC * kF * 4);
        for (int pair = 0; pair < kB * kE; pair++) {
            ngemm1_k<<<dim3(kF / 64, kC / 64), dim3(16, 16), 0, stream>>>(
                hidden, wi, slot_token, counts, H, pair);
            ngemm2_k<<<dim3(kD / 64, kC / 64), dim3(16, 16), 0, stream>>>(
                H, wo, slot_token, counts, maxprob, outp, pair);
        }
    }
}

// Round 12
// 885.991 us; speedup vs baseline: 1.3143x; 1.3143x over previous
//
#include <hip/hip_runtime.h>
#include <stdint.h>

static constexpr int kB = 8, kS = 2048, kD = 1024, kF = 4096, kE = 8, kC = 512;

typedef unsigned short u16;
typedef __attribute__((ext_vector_type(8))) short bf16x8;
typedef __attribute__((ext_vector_type(4))) float f32x4;

__device__ __forceinline__ u16 f2bf(float f) {
    union { float f; uint32_t u; } v; v.f = f;
    return (u16)((v.u + 0x7fffu + ((v.u >> 16) & 1u)) >> 16);
}
__device__ __forceinline__ void gload16(const u16* g, u16* l) {
    __builtin_amdgcn_global_load_lds(
        (__attribute__((address_space(1))) void*)(u16*)g,
        (__attribute__((address_space(3))) void*)l, 16, 0, 0);
}

static constexpr int kSmemBytes = 132096;  // A 64KB + B 64KB + slots 1KB

// ---------------- init: zero the fp32 `out` region of d_out ----------------
__global__ void init_k(uint4* __restrict__ outz) {
    const size_t n = (size_t)kB * kS * kD * 4 / 16;
    size_t stride = (size_t)gridDim.x * blockDim.x;
    for (size_t i = (size_t)blockIdx.x * blockDim.x + threadIdx.x; i < n; i += stride)
        outz[i] = (uint4){0, 0, 0, 0};
}

// ---------------- hidden fp32 -> bf16 image; block 0 also zeroes the zero page ----------------
__global__ void conv_hidden_k(const float* __restrict__ src, u16* __restrict__ hbf,
                              uint4* __restrict__ zerobuf) {
    if (blockIdx.x == 0 && threadIdx.x < 144) zerobuf[threadIdx.x] = (uint4){0, 0, 0, 0};
    const size_t n = (size_t)kB * kS * kD;
    size_t i0 = ((size_t)blockIdx.x * blockDim.x + threadIdx.x) * 8;
    size_t stride = (size_t)gridDim.x * blockDim.x * 8;
    for (size_t i = i0; i < n; i += stride) {
        float4 a = *(const float4*)(src + i);
        float4 b = *(const float4*)(src + i + 4);
        u16 t[8] = {f2bf(a.x), f2bf(a.y), f2bf(a.z), f2bf(a.w),
                    f2bf(b.x), f2bf(b.y), f2bf(b.z), f2bf(b.w)};
        *(uint4*)(hbf + i) = *(const uint4*)t;
    }
}

// ---------------- router: fp32 logits, softmax, first-wins argmax (proven) ----------
__global__ __launch_bounds__(256) void router_k(
    const float* __restrict__ hidden, const float* __restrict__ rw,
    float* __restrict__ logits_out, int* __restrict__ expert_id, float* __restrict__ maxprob)
{
    int token = blockIdx.x * 4 + (threadIdx.x >> 6);
    int lane = threadIdx.x & 63;
    const float* hrow = hidden + (size_t)token * kD;
    float acc[8] = {0, 0, 0, 0, 0, 0, 0, 0};
    for (int d0 = lane * 4; d0 < kD; d0 += 256) {
        float4 h4 = *(const float4*)(hrow + d0);
        float hv[4] = {h4.x, h4.y, h4.z, h4.w};
        #pragma unroll
        for (int j = 0; j < 4; j++) {
            const float* wr = rw + (size_t)(d0 + j) * 8;
            float4 w0 = *(const float4*)wr, w1 = *(const float4*)(wr + 4);
            acc[0] += hv[j] * w0.x; acc[1] += hv[j] * w0.y;
            acc[2] += hv[j] * w0.z; acc[3] += hv[j] * w0.w;
            acc[4] += hv[j] * w1.x; acc[5] += hv[j] * w1.y;
            acc[6] += hv[j] * w1.z; acc[7] += hv[j] * w1.w;
        }
    }
    #pragma unroll
    for (int off = 32; off >= 1; off >>= 1) {
        #pragma unroll
        for (int e = 0; e < 8; e++) acc[e] += __shfl_down(acc[e], off, 64);
    }
    if (lane == 0) {
        float m = acc[0];
        #pragma unroll
        for (int e = 1; e < 8; e++) m = fmaxf(m, acc[e]);
        float ex[8], s = 0.f;
        #pragma unroll
        for (int e = 0; e < 8; e++) { ex[e] = expf(acc[e] - m); s += ex[e]; }
        int best = 0; float bv = -1.f;
        #pragma unroll
        for (int e = 0; e < 8; e++) {
            float p = ex[e] / s;
            if (p > bv) { bv = p; best = e; }
            logits_out[(size_t)token * 8 + e] = acc[e];
        }
        expert_id[token] = best;
        maxprob[token] = bv;
    }
}

// ---------------- capacity scan (proven) ----------------
__global__ __launch_bounds__(64) void scan_k(
    const int* __restrict__ expert_id, int* __restrict__ slot_token,
    int* __restrict__ counts, float* __restrict__ expidx_out)
{
    __shared__ int eids[kS];
    int b = blockIdx.x, tid = threadIdx.x;
    for (int s = tid; s < kS; s += 64) eids[s] = expert_id[b * kS + s];
    __syncthreads();
    if (tid < kE) {
        int e = tid, cnt = 0;
        for (int s = 0; s < kS; s++) {
            if (eids[s] == e) {
                if (cnt < kC) {
                    slot_token[(b * kE + e) * kC + cnt] = s;
                    expidx_out[b * kS + s] = (float)e;
                    cnt++;
                } else {
                    expidx_out[b * kS + s] = 0.f;
                }
            }
        }
        counts[b * kE + e] = cnt;
        for (int c = cnt; c < kC; c++) slot_token[(b * kE + e) * kC + c] = -1;
    }
}

// ---------------- transpose fp32 [R][Cn] -> bf16 [Cn][R]; blockIdx.z = expert ----------------
__global__ void transpose_k(const float* __restrict__ src, u16* __restrict__ dst, int R, int Cn) {
    __shared__ u16 t[32][33];
    size_t eo = (size_t)blockIdx.z * R * Cn;
    int c0 = blockIdx.x * 32, r0 = blockIdx.y * 32;
    int tx = threadIdx.x, ty = threadIdx.y;
    #pragma unroll
    for (int i = 0; i < 4; i++)
        t[ty + i * 8][tx] = f2bf(src[eo + (size_t)(r0 + ty + i * 8) * Cn + c0 + tx]);
    __syncthreads();
    #pragma unroll
    for (int i = 0; i < 4; i++)
        dst[eo + (size_t)(c0 + ty + i * 8) * R + r0 + tx] = t[tx][ty + i * 8];
}

// ================= 8-phase 256x256 MFMA GEMM kernels =================
// LDS per operand: [2 buf][2 khalf][256 rows][32 k] bf16 (16B-unit swizzle
// c' = c ^ ((r>>1)&3) applied on stage-SOURCE and on fragment reads).
// Schedule (per iteration = K-tiles 2i,2i+1): stage slots
// P1:B(2i+1,kh1) P2:A(2i+2,kh0) P3:B(2i+2,kh0) P4:A(2i+2,kh1) P5:B(2i+2,kh1)
// P6:A(2i+3,kh0) P7:B(2i+3,kh0) P8:A(2i+3,kh1); vmcnt(6) at P4/P8 only.

#define SA8(kt, kh) { int off_ = (((kt) & 1) << 14) + ((kh) << 13); int go_ = (kt) * 64 + (kh) * 32; \
    gload16(sA0 + go_, dA + off_); gload16(sA1 + go_, dA + off_ + 512); }
#define SB8(kt, kh) { int off_ = (((kt) & 1) << 14) + ((kh) << 13); int go_ = (kt) * 64 + (kh) * 32; \
    gload16(sB0 + go_, dB + off_); gload16(sB1 + go_, dB + off_ + 512); }
#define RD8(buf, kh) { const u16* a_ = rA + ((buf) << 14) + ((kh) << 13); \
    const u16* b_ = rB + ((buf) << 14) + ((kh) << 13); \
    _Pragma("unroll") for (int m_ = 0; m_ < 8; m_++) af[m_] = *(const bf16x8*)(a_ + m_ * 512); \
    _Pragma("unroll") for (int n_ = 0; n_ < 4; n_++) bfr[n_] = *(const bf16x8*)(b_ + n_ * 512); }
#define MM8(mlo) { _Pragma("unroll") for (int m_ = 0; m_ < 4; m_++) \
    { _Pragma("unroll") for (int n_ = 0; n_ < 4; n_++) \
      acc[(mlo) + m_][n_] = __builtin_amdgcn_mfma_f32_16x16x32_bf16(af[(mlo) + m_], bfr[n_], acc[(mlo) + m_][n_], 0, 0, 0); } }
#define PH_MID() __builtin_amdgcn_sched_barrier(0); __builtin_amdgcn_s_barrier(); \
    asm volatile("s_waitcnt lgkmcnt(0)" ::: "memory"); __builtin_amdgcn_sched_barrier(0); \
    __builtin_amdgcn_s_setprio(1)
#define PH_END() __builtin_amdgcn_s_setprio(0); __builtin_amdgcn_sched_barrier(0); \
    __builtin_amdgcn_s_barrier(); __builtin_amdgcn_sched_barrier(0)
#define PH_END_VM(n) __builtin_amdgcn_s_setprio(0); __builtin_amdgcn_sched_barrier(0); \
    asm volatile("s_waitcnt vmcnt(" #n ")" ::: "memory"); \
    __builtin_amdgcn_s_barrier(); __builtin_amdgcn_sched_barrier(0)

// ---------------- GEMM1 (8-phase): H = relu(gather(hbf) @ wiT^T), bf16 H ----------------
__global__ __launch_bounds__(512, 1) void gemm1_8p(
    const u16* __restrict__ hbf, const u16* __restrict__ wiT, size_t wstride,
    const int* __restrict__ slot_token, const int* __restrict__ counts,
    const u16* __restrict__ zerobuf, u16* __restrict__ Hbuf, int p0)
{
    constexpr int KDIM = kD, NTn = kF / 256, NKT = KDIM / 64, NI = NKT / 2;
    int bid = blockIdx.x;
    int nt = bid % NTn;
    int g = bid / NTn;
    int mt = g & 1, pl = g >> 1;
    int pem = p0 + pl;
    int e = pem >> 3, b = pem & 7;
    int pair = b * kE + e;
    int cnt = counts[pair];
    if (mt * 256 >= cnt) return;

    int tid = threadIdx.x, w = tid >> 6, l = tid & 63;
    int wr = w >> 2, wc = w & 3;
    int fr = l & 15, fq = l >> 4;

    extern __shared__ __align__(16) u16 lds[];
    u16* Ap = lds;
    u16* Bp = lds + 32768;
    int* slots = (int*)(lds + 65536);
    if (tid < 256) slots[tid] = slot_token[pair * kC + mt * 256 + tid];
    __syncthreads();

    int r0 = w * 32 + (l >> 2), r1 = r0 + 16;
    int clog = (l & 3) ^ ((l >> 3) & 3);
    int sl0 = slots[r0], sl1 = slots[r1];
    const u16* sA0 = (sl0 >= 0) ? hbf + (size_t)(b * kS + sl0) * kD + clog * 8 : zerobuf + clog * 8;
    const u16* sA1 = (sl1 >= 0) ? hbf + (size_t)(b * kS + sl1) * kD + clog * 8 : zerobuf + clog * 8;
    const u16* wbase = wiT + (size_t)e * wstride;
    const u16* sB0 = wbase + (size_t)(nt * 256 + r0) * KDIM + clog * 8;
    const u16* sB1 = wbase + (size_t)(nt * 256 + r1) * KDIM + clog * 8;
    u16* dA = Ap + w * 1024;
    u16* dB = Bp + w * 1024;

    int sw = (fr >> 1) & 3;
    const u16* rA = Ap + (wr * 128 + fr) * 32 + ((fq ^ sw) << 3);
    const u16* rB = Bp + (wc * 64 + fr) * 32 + ((fq ^ sw) << 3);

    f32x4 acc[8][4];
    #pragma unroll
    for (int m = 0; m < 8; m++)
        #pragma unroll
        for (int n = 0; n < 4; n++) acc[m][n] = (f32x4){0.f, 0.f, 0.f, 0.f};
    bf16x8 af[8], bfr[4];

    // prologue: tile0 full + tile1 minus B.kh1
    SA8(0, 0) SB8(0, 0) SA8(0, 1) SB8(0, 1) SA8(1, 0) SB8(1, 0) SA8(1, 1)
    asm volatile("s_waitcnt vmcnt(6)" ::: "memory");
    __builtin_amdgcn_s_barrier();
    __builtin_amdgcn_sched_barrier(0);

    #pragma unroll 1
    for (int i = 0; i < NI - 1; ++i) {
        int kt0 = 2 * i;
        RD8(0, 0) SB8(kt0 + 1, 1) PH_MID(); MM8(0) PH_END();                 // P1
        SA8(kt0 + 2, 0)           PH_MID(); MM8(4) PH_END();                 // P2
        RD8(0, 1) SB8(kt0 + 2, 0) PH_MID(); MM8(0) PH_END();                 // P3
        SA8(kt0 + 2, 1)           PH_MID(); MM8(4) PH_END_VM(6);             // P4
        RD8(1, 0) SB8(kt0 + 2, 1) PH_MID(); MM8(0) PH_END();                 // P5
        SA8(kt0 + 3, 0)           PH_MID(); MM8(4) PH_END();                 // P6
        RD8(1, 1) SB8(kt0 + 3, 0) PH_MID(); MM8(0) PH_END();                 // P7
        SA8(kt0 + 3, 1)           PH_MID(); MM8(4) PH_END_VM(6);             // P8
    }
    // last iteration (K-tiles NKT-2, NKT-1): only the P1 stage; vmcnt(0) at P4
    RD8(0, 0) SB8(NKT - 1, 1) PH_MID(); MM8(0) PH_END();
    PH_MID(); MM8(4) PH_END();
    RD8(0, 1) PH_MID(); MM8(0) PH_END();
    PH_MID(); MM8(4) PH_END_VM(0);
    RD8(1, 0) PH_MID(); MM8(0) PH_END();
    PH_MID(); MM8(4) PH_END();
    RD8(1, 1) PH_MID(); MM8(0) PH_END();
    PH_MID(); MM8(4) __builtin_amdgcn_s_setprio(0); __builtin_amdgcn_sched_barrier(0);

    size_t hbase = (size_t)pl * kC * kF;
    int rbase = mt * 256 + wr * 128, c0 = nt * 256 + wc * 64;
    #pragma unroll
    for (int m = 0; m < 8; m++) {
        #pragma unroll
        for (int j = 0; j < 4; j++) {
            int row = rbase + m * 16 + fq * 4 + j;
            size_t rb = hbase + (size_t)row * kF;
            #pragma unroll
            for (int n = 0; n < 4; n++)
                Hbuf[rb + c0 + n * 16 + fr] = f2bf(fmaxf(acc[m][n][j], 0.f));
        }
    }
}

// ---------------- GEMM2 (8-phase): out = (H @ woT^T) * max_prob, fp32 scatter ----------------
__global__ __launch_bounds__(512, 1) void gemm2_8p(
    const u16* __restrict__ Hbuf, const u16* __restrict__ woT, size_t wstride,
    const int* __restrict__ slot_token, const int* __restrict__ counts,
    const float* __restrict__ maxprob, float* __restrict__ outp, int p0)
{
    constexpr int KDIM = kF, NTn = kD / 256, NKT = KDIM / 64, NI = NKT / 2;
    int bid = blockIdx.x;
    int nt = bid % NTn;
    int g = bid / NTn;
    int mt = g & 1, pl = g >> 1;
    int pem = p0 + pl;
    int e = pem >> 3, b = pem & 7;
    int pair = b * kE + e;
    int cnt = counts[pair];
    if (mt * 256 >= cnt) return;

    int tid = threadIdx.x, w = tid >> 6, l = tid & 63;
    int wr = w >> 2, wc = w & 3;
    int fr = l & 15, fq = l >> 4;

    extern __shared__ __align__(16) u16 lds[];
    u16* Ap = lds;
    u16* Bp = lds + 32768;
    int* slots = (int*)(lds + 65536);
    if (tid < 256) slots[tid] = slot_token[pair * kC + mt * 256 + tid];
    __syncthreads();

    int r0 = w * 32 + (l >> 2), r1 = r0 + 16;
    int clog = (l & 3) ^ ((l >> 3) & 3);
    const u16* sA0 = Hbuf + ((size_t)pl * kC + mt * 256 + r0) * kF + clog * 8;
    const u16* sA1 = Hbuf + ((size_t)pl * kC + mt * 256 + r1) * kF + clog * 8;
    const u16* wbase = woT + (size_t)e * wstride;
    const u16* sB0 = wbase + (size_t)(nt * 256 + r0) * KDIM + clog * 8;
    const u16* sB1 = wbase + (size_t)(nt * 256 + r1) * KDIM + clog * 8;
    u16* dA = Ap + w * 1024;
    u16* dB = Bp + w * 1024;

    int sw = (fr >> 1) & 3;
    const u16* rA = Ap + (wr * 128 + fr) * 32 + ((fq ^ sw) << 3);
    const u16* rB = Bp + (wc * 64 + fr) * 32 + ((fq ^ sw) << 3);

    f32x4 acc[8][4];
    #pragma unroll
    for (int m = 0; m < 8; m++)
        #pragma unroll
        for (int n = 0; n < 4; n++) acc[m][n] = (f32x4){0.f, 0.f, 0.f, 0.f};
    bf16x8 af[8], bfr[4];

    SA8(0, 0) SB8(0, 0) SA8(0, 1) SB8(0, 1) SA8(1, 0) SB8(1, 0) SA8(1, 1)
    asm volatile("s_waitcnt vmcnt(6)" ::: "memory");
    __builtin_amdgcn_s_barrier();
    __builtin_amdgcn_sched_barrier(0);

    #pragma unroll 1
    for (int i = 0; i < NI - 1; ++i) {
        int kt0 = 2 * i;
        RD8(0, 0) SB8(kt0 + 1, 1) PH_MID(); MM8(0) PH_END();
        SA8(kt0 + 2, 0)           PH_MID(); MM8(4) PH_END();
        RD8(0, 1) SB8(kt0 + 2, 0) PH_MID(); MM8(0) PH_END();
        SA8(kt0 + 2, 1)           PH_MID(); MM8(4) PH_END_VM(6);
        RD8(1, 0) SB8(kt0 + 2, 1) PH_MID(); MM8(0) PH_END();
        SA8(kt0 + 3, 0)           PH_MID(); MM8(4) PH_END();
        RD8(1, 1) SB8(kt0 + 3, 0) PH_MID(); MM8(0) PH_END();
        SA8(kt0 + 3, 1)           PH_MID(); MM8(4) PH_END_VM(6);
    }
    RD8(0, 0) SB8(NKT - 1, 1) PH_MID(); MM8(0) PH_END();
    PH_MID(); MM8(4) PH_END();
    RD8(0, 1) PH_MID(); MM8(0) PH_END();
    PH_MID(); MM8(4) PH_END_VM(0);
    RD8(1, 0) PH_MID(); MM8(0) PH_END();
    PH_MID(); MM8(4) PH_END();
    RD8(1, 1) PH_MID(); MM8(0) PH_END();
    PH_MID(); MM8(4) __builtin_amdgcn_s_setprio(0); __builtin_amdgcn_sched_barrier(0);

    int c0 = nt * 256 + wc * 64;
    #pragma unroll
    for (int m = 0; m < 8; m++) {
        #pragma unroll
        for (int j = 0; j < 4; j++) {
            int rl = wr * 128 + m * 16 + fq * 4 + j;
            int s = slots[rl];
            if (s >= 0) {
                float p = maxprob[b * kS + s];
                size_t ob = (size_t)(b * kS + s) * kD;
                #pragma unroll
                for (int n = 0; n < 4; n++)
                    outp[ob + c0 + n * 16 + fr] = acc[m][n][j] * p;
            }
        }
    }
}

#undef SA8
#undef SB8
#undef RD8
#undef MM8
#undef PH_MID
#undef PH_END
#undef PH_END_VM

// ---------------- naive fp32 fallback (proven) ----------------
__global__ __launch_bounds__(256) void ngemm1_k(
    const float* __restrict__ hidden, const float* __restrict__ wi,
    const int* __restrict__ slot_token, const int* __restrict__ counts,
    float* __restrict__ H, int pair)
{
    int b = pair >> 3, e = pair & 7;
    int cnt = counts[pair];
    int c0 = blockIdx.y * 64, f0 = blockIdx.x * 64;
    if (c0 >= cnt) return;
    __shared__ float As[64][17];
    __shared__ float Bs[16][65];
    __shared__ int slots[64];
    int tx = threadIdx.x, ty = threadIdx.y;
    int tid = ty * 16 + tx;
    if (tid < 64) slots[tid] = slot_token[pair * kC + c0 + tid];
    __syncthreads();
    float acc[4][4];
    #pragma unroll
    for (int i = 0; i < 4; i++)
        #pragma unroll
        for (int j = 0; j < 4; j++) acc[i][j] = 0.f;
    int ar = tid >> 2, ak = (tid & 3) * 4;
    int bd = tid >> 4, bf = (tid & 15) * 4;
    const float* wie = wi + (size_t)e * kD * kF;
    for (int k0 = 0; k0 < kD; k0 += 16) {
        int sl = slots[ar];
        if (sl >= 0) {
            float4 v = *(const float4*)(hidden + (size_t)(b * kS + sl) * kD + k0 + ak);
            As[ar][ak] = v.x; As[ar][ak + 1] = v.y; As[ar][ak + 2] = v.z; As[ar][ak + 3] = v.w;
        } else {
            As[ar][ak] = 0.f; As[ar][ak + 1] = 0.f; As[ar][ak + 2] = 0.f; As[ar][ak + 3] = 0.f;
        }
        float4 wv = *(const float4*)(wie + (size_t)(k0 + bd) * kF + f0 + bf);
        Bs[bd][bf] = wv.x; Bs[bd][bf + 1] = wv.y; Bs[bd][bf + 2] = wv.z; Bs[bd][bf + 3] = wv.w;
        __syncthreads();
        #pragma unroll
        for (int kk = 0; kk < 16; kk++) {
            float a[4], bv[4];
            #pragma unroll
            for (int i = 0; i < 4; i++) a[i] = As[ty * 4 + i][kk];
            #pragma unroll
            for (int j = 0; j < 4; j++) bv[j] = Bs[kk][tx * 4 + j];
            #pragma unroll
            for (int i = 0; i < 4; i++)
                #pragma unroll
                for (int j = 0; j < 4; j++) acc[i][j] += a[i] * bv[j];
        }
        __syncthreads();
    }
    #pragma unroll
    for (int i = 0; i < 4; i++) {
        int row = c0 + ty * 4 + i;
        #pragma unroll
        for (int j = 0; j < 4; j++)
            H[(size_t)row * kF + f0 + tx * 4 + j] = fmaxf(acc[i][j], 0.f);
    }
}

__global__ __launch_bounds__(256) void ngemm2_k(
    const float* __restrict__ H, const float* __restrict__ wo,
    const int* __restrict__ slot_token, const int* __restrict__ counts,
    const float* __restrict__ maxprob, float* __restrict__ outp, int pair)
{
    int b = pair >> 3, e = pair & 7;
    int cnt = counts[pair];
    int c0 = blockIdx.y * 64, d0 = blockIdx.x * 64;
    if (c0 >= cnt) return;
    __shared__ float As[64][17];
    __shared__ float Bs[16][65];
    __shared__ int slots[64];
    int tx = threadIdx.x, ty = threadIdx.y;
    int tid = ty * 16 + tx;
    if (tid < 64) slots[tid] = slot_token[pair * kC + c0 + tid];
    __syncthreads();
    float acc[4][4];
    #pragma unroll
    for (int i = 0; i < 4; i++)
        #pragma unroll
        for (int j = 0; j < 4; j++) acc[i][j] = 0.f;
    int ar = tid >> 2, ak = (tid & 3) * 4;
    int bd = tid >> 4, bf = (tid & 15) * 4;
    const float* woe = wo + (size_t)e * kF * kD;
    for (int k0 = 0; k0 < kF; k0 += 16) {
        float4 v = *(const float4*)(H + (size_t)(c0 + ar) * kF + k0 + ak);
        As[ar][ak] = v.x; As[ar][ak + 1] = v.y; As[ar][ak + 2] = v.z; As[ar][ak + 3] = v.w;
        float4 wv = *(const float4*)(woe + (size_t)(k0 + bd) * kD + d0 + bf);
        Bs[bd][bf] = wv.x; Bs[bd][bf + 1] = wv.y; Bs[bd][bf + 2] = wv.z; Bs[bd][bf + 3] = wv.w;
        __syncthreads();
        #pragma unroll
        for (int kk = 0; kk < 16; kk++) {
            float a[4], bv[4];
            #pragma unroll
            for (int i = 0; i < 4; i++) a[i] = As[ty * 4 + i][kk];
            #pragma unroll
            for (int j = 0; j < 4; j++) bv[j] = Bs[kk][tx * 4 + j];
            #pragma unroll
            for (int i = 0; i < 4; i++)
                #pragma unroll
                for (int j = 0; j < 4; j++) acc[i][j] += a[i] * bv[j];
        }
        __syncthreads();
    }
    #pragma unroll
    for (int i = 0; i < 4; i++) {
        int s = slots[ty * 4 + i];
        if (s >= 0) {
            float p = maxprob[b * kS + s];
            size_t ob = (size_t)(b * kS + s) * kD;
            #pragma unroll
            for (int j = 0; j < 4; j++)
                outp[ob + d0 + tx * 4 + j] = acc[i][j] * p;
        }
    }
}

extern "C" void kernel_launch(void* const* d_in, const int* in_sizes, int n_in,
                              void* d_out, int out_size, void* d_ws, size_t ws_size,
                              hipStream_t stream)
{
    const float* hidden = (const float*)d_in[0];
    const float* rw     = (const float*)d_in[1];
    const float* wi     = (const float*)d_in[2];
    const float* wo     = (const float*)d_in[3];
    float* outp   = (float*)d_out;
    float* logits = outp + (size_t)kB * kS * kD;
    float* expidx = logits + (size_t)kB * kS * kE;

    char* ws = (char*)d_ws;
    size_t off = 0;
    auto alloc = [&](size_t bytes) -> char* {
        char* p = ws + off; off += (bytes + 255) & ~(size_t)255; return p;
    };
    int*   slot_token = (int*)  alloc((size_t)kB * kE * kC * 4);
    int*   counts     = (int*)  alloc((size_t)kB * kE * 4);
    int*   expert_id  = (int*)  alloc((size_t)kB * kS * 4);
    float* maxprob    = (float*)alloc((size_t)kB * kS * 4);
    size_t small_off = off;

    const size_t wsz   = (size_t)kD * kF * 2;       // 8 MiB per expert, bf16
    const size_t hsz   = (size_t)kC * kF * 2;       // 4 MiB per pair, bf16
    const size_t hbfsz = (size_t)kB * kS * kD * 2;  // 32 MiB bf16 hidden image

    init_k<<<2048, 256, 0, stream>>>((uint4*)outp);
    router_k<<<kB * kS / 4, 256, 0, stream>>>(hidden, rw, logits, expert_id, maxprob);
    scan_k<<<kB, 64, 0, stream>>>(expert_id, slot_token, counts, expidx);

    hipFuncSetAttribute(reinterpret_cast<const void*>(gemm1_8p),
                        hipFuncAttributeMaxDynamicSharedMemorySize, kSmemBytes);
    hipFuncSetAttribute(reinterpret_cast<const void*>(gemm2_8p),
                        hipFuncAttributeMaxDynamicSharedMemorySize, kSmemBytes);

    if (ws_size >= small_off + 2 * kE * wsz + hbfsz + 4096 + 4 * hsz) {
        // ---- tier A: all-expert transposed weights + bf16 hidden image ----
        u16* wiT = (u16*)alloc(kE * wsz);   // 64 MiB
        u16* woT = (u16*)alloc(kE * wsz);   // 64 MiB
        u16* hbf = (u16*)alloc(hbfsz);      // 32 MiB
        u16* zerobuf = (u16*)alloc(4096);
        int Gb = (int)((ws_size - off) / hsz);
        if (Gb > kB * kE) Gb = kB * kE;
        if (Gb < 1) Gb = 1;
        u16* Hbuf = (u16*)alloc((size_t)Gb * hsz);
        conv_hidden_k<<<2048, 256, 0, stream>>>(hidden, hbf, (uint4*)zerobuf);
        transpose_k<<<dim3(kF / 32, kD / 32, kE), dim3(32, 8), 0, stream>>>(wi, wiT, kD, kF);
        transpose_k<<<dim3(kD / 32, kF / 32, kE), dim3(32, 8), 0, stream>>>(wo, woT, kF, kD);
        for (int p0 = 0; p0 < kB * kE; p0 += Gb) {
            int g = kB * kE - p0 < Gb ? kB * kE - p0 : Gb;
            gemm1_8p<<<g * 2 * (kF / 256), 512, kSmemBytes, stream>>>(
                hbf, wiT, (size_t)kD * kF, slot_token, counts, zerobuf, Hbuf, p0);
            gemm2_8p<<<g * 2 * (kD / 256), 512, kSmemBytes, stream>>>(
                Hbuf, woT, (size_t)kD * kF, slot_token, counts, maxprob, outp, p0);
        }
    } else if (ws_size >= small_off + 2 * wsz + hbfsz + 4096 + hsz) {
        // ---- tier B: per-expert transposed weights (same 8p kernels, wstride=0) ----
        u16* wiT = (u16*)alloc(wsz);
        u16* woT = (u16*)alloc(wsz);
        u16* hbf = (u16*)alloc(hbfsz);
        u16* zerobuf = (u16*)alloc(4096);
        int Gb = (int)((ws_size - off) / hsz);
        if (Gb > kB) Gb = kB;
        if (Gb < 1) Gb = 1;
        u16* Hbuf = (u16*)alloc((size_t)Gb * hsz);
        conv_hidden_k<<<2048, 256, 0, stream>>>(hidden, hbf, (uint4*)zerobuf);
        for (int e = 0; e < kE; e++) {
            transpose_k<<<dim3(kF / 32, kD / 32, 1), dim3(32, 8), 0, stream>>>(
                wi + (size_t)e * kD * kF, wiT, kD, kF);
            transpose_k<<<dim3(kD / 32, kF / 32, 1), dim3(32, 8), 0, stream>>>(
                wo + (size_t)e * kD * kF, woT, kF, kD);
            for (int b0 = 0; b0 < kB; b0 += Gb) {
                int g = kB - b0 < Gb ? kB - b0 : Gb;
                int p0 = e * 8 + b0;   // expert-major pem space
                gemm1_8p<<<g * 2 * (kF / 256), 512, kSmemBytes, stream>>>(
                    hbf, wiT, 0, slot_token, counts, zerobuf, Hbuf, p0);
                gemm2_8p<<<g * 2 * (kD / 256), 512, kSmemBytes, stream>>>(
                    Hbuf, woT, 0, slot_token, counts, maxprob, outp, p0);
            }
        }
    } else {
        // ---- tier C: proven naive fp32 fallback ----
        float* H = (float*)alloc((size_t)kC * kF * 4);
        for (int pair = 0; pair < kB * kE; pair++) {
            ngemm1_k<<<dim3(kF / 64, kC / 64), dim3(16, 16), 0, stream>>>(
                hidden, wi, slot_token, counts, H, pair);
            ngemm2_k<<<dim3(kD / 64, kC / 64), dim3(16, 16), 0, stream>>>(
                H, wo, slot_token, counts, maxprob, outp, pair);
        }
    }
}

// Round 13
// 870.862 us; speedup vs baseline: 1.3371x; 1.0174x over previous
//
#include <hip/hip_runtime.h>
#include <stdint.h>

static constexpr int kB = 8, kS = 2048, kD = 1024, kF = 4096, kE = 8, kC = 512;

typedef unsigned short u16;
typedef __attribute__((ext_vector_type(8))) short bf16x8;
typedef __attribute__((ext_vector_type(4))) float f32x4;

__device__ __forceinline__ u16 f2bf(float f) {
    union { float f; uint32_t u; } v; v.f = f;
    return (u16)((v.u + 0x7fffu + ((v.u >> 16) & 1u)) >> 16);
}
__device__ __forceinline__ void gload16(const u16* g, u16* l) {
    __builtin_amdgcn_global_load_lds(
        (__attribute__((address_space(1))) void*)(u16*)g,
        (__attribute__((address_space(3))) void*)l, 16, 0, 0);
}

static constexpr int kSmemBytes = 132096;  // A 64KB + B 64KB + slots 1KB

// ---------------- init: zero the fp32 `out` region of d_out + zero page ----------------
__global__ void init_k(uint4* __restrict__ outz, uint4* __restrict__ zb) {
    if (blockIdx.x == 0 && zb && threadIdx.x < 256) zb[threadIdx.x] = (uint4){0, 0, 0, 0};
    const size_t n = (size_t)kB * kS * kD * 4 / 16;
    size_t stride = (size_t)gridDim.x * blockDim.x;
    for (size_t i = (size_t)blockIdx.x * blockDim.x + threadIdx.x; i < n; i += stride)
        outz[i] = (uint4){0, 0, 0, 0};
}

// ---------------- router (fused): fp32 logits + argmax + writes bf16 hidden image ----------
__global__ __launch_bounds__(256) void router_k(
    const float* __restrict__ hidden, const float* __restrict__ rw,
    float* __restrict__ logits_out, int* __restrict__ expert_id, float* __restrict__ maxprob,
    u16* __restrict__ hbf)
{
    int token = blockIdx.x * 4 + (threadIdx.x >> 6);
    int lane = threadIdx.x & 63;
    const float* hrow = hidden + (size_t)token * kD;
    float acc[8] = {0, 0, 0, 0, 0, 0, 0, 0};
    for (int d0 = lane * 4; d0 < kD; d0 += 256) {
        float4 h4 = *(const float4*)(hrow + d0);
        float hv[4] = {h4.x, h4.y, h4.z, h4.w};
        if (hbf) {   // fused fp32->bf16 image write (uniform branch)
            u16 t4[4] = {f2bf(h4.x), f2bf(h4.y), f2bf(h4.z), f2bf(h4.w)};
            *(uint2*)(hbf + (size_t)token * kD + d0) = *(const uint2*)t4;
        }
        #pragma unroll
        for (int j = 0; j < 4; j++) {
            const float* wr = rw + (size_t)(d0 + j) * 8;
            float4 w0 = *(const float4*)wr, w1 = *(const float4*)(wr + 4);
            acc[0] += hv[j] * w0.x; acc[1] += hv[j] * w0.y;
            acc[2] += hv[j] * w0.z; acc[3] += hv[j] * w0.w;
            acc[4] += hv[j] * w1.x; acc[5] += hv[j] * w1.y;
            acc[6] += hv[j] * w1.z; acc[7] += hv[j] * w1.w;
        }
    }
    #pragma unroll
    for (int off = 32; off >= 1; off >>= 1) {
        #pragma unroll
        for (int e = 0; e < 8; e++) acc[e] += __shfl_down(acc[e], off, 64);
    }
    if (lane == 0) {
        float m = acc[0];
        #pragma unroll
        for (int e = 1; e < 8; e++) m = fmaxf(m, acc[e]);
        float ex[8], s = 0.f;
        #pragma unroll
        for (int e = 0; e < 8; e++) { ex[e] = expf(acc[e] - m); s += ex[e]; }
        int best = 0; float bv = -1.f;
        #pragma unroll
        for (int e = 0; e < 8; e++) {
            float p = ex[e] / s;
            if (p > bv) { bv = p; best = e; }
            logits_out[(size_t)token * 8 + e] = acc[e];
        }
        expert_id[token] = best;
        maxprob[token] = bv;
    }
}

// ---------------- capacity scan (proven) ----------------
__global__ __launch_bounds__(64) void scan_k(
    const int* __restrict__ expert_id, int* __restrict__ slot_token,
    int* __restrict__ counts, float* __restrict__ expidx_out)
{
    __shared__ int eids[kS];
    int b = blockIdx.x, tid = threadIdx.x;
    for (int s = tid; s < kS; s += 64) eids[s] = expert_id[b * kS + s];
    __syncthreads();
    if (tid < kE) {
        int e = tid, cnt = 0;
        for (int s = 0; s < kS; s++) {
            if (eids[s] == e) {
                if (cnt < kC) {
                    slot_token[(b * kE + e) * kC + cnt] = s;
                    expidx_out[b * kS + s] = (float)e;
                    cnt++;
                } else {
                    expidx_out[b * kS + s] = 0.f;
                }
            }
        }
        counts[b * kE + e] = cnt;
        for (int c = cnt; c < kC; c++) slot_token[(b * kE + e) * kC + c] = -1;
    }
}

// ---------------- vectorized convert-transpose: fp32 [R][Cn] -> bf16 [Cn][R] ----------------
// 64x64 tiles; float4 loads, uint4 stores. blockIdx.z = expert slice.
__global__ __launch_bounds__(256) void transpose_v(
    const float* __restrict__ src, u16* __restrict__ dst, int R, int Cn)
{
    __shared__ u16 tl[64][68];
    size_t eo = (size_t)blockIdx.z * R * Cn;
    int c0 = blockIdx.x * 64, r0 = blockIdx.y * 64;
    int t = threadIdx.x;
    int tx = t & 15, ty = t >> 4;
    #pragma unroll
    for (int i = 0; i < 4; i++) {
        int r = ty + 16 * i;
        float4 v = *(const float4*)(src + eo + (size_t)(r0 + r) * Cn + c0 + tx * 4);
        tl[tx * 4 + 0][r] = f2bf(v.x);
        tl[tx * 4 + 1][r] = f2bf(v.y);
        tl[tx * 4 + 2][r] = f2bf(v.z);
        tl[tx * 4 + 3][r] = f2bf(v.w);
    }
    __syncthreads();
    int seg = t & 7, clb = t >> 3;
    #pragma unroll
    for (int ii = 0; ii < 2; ii++) {
        int cl = clb + 32 * ii;
        uint4 v = *(const uint4*)&tl[cl][seg * 8];
        *(uint4*)(dst + eo + (size_t)(c0 + cl) * R + r0 + seg * 8) = v;
    }
}

// ================= 8-phase 256x256 MFMA GEMM kernels (round-12 proven, unchanged) =========
#define SA8(kt, kh) { int off_ = (((kt) & 1) << 14) + ((kh) << 13); int go_ = (kt) * 64 + (kh) * 32; \
    gload16(sA0 + go_, dA + off_); gload16(sA1 + go_, dA + off_ + 512); }
#define SB8(kt, kh) { int off_ = (((kt) & 1) << 14) + ((kh) << 13); int go_ = (kt) * 64 + (kh) * 32; \
    gload16(sB0 + go_, dB + off_); gload16(sB1 + go_, dB + off_ + 512); }
#define RD8(buf, kh) { const u16* a_ = rA + ((buf) << 14) + ((kh) << 13); \
    const u16* b_ = rB + ((buf) << 14) + ((kh) << 13); \
    _Pragma("unroll") for (int m_ = 0; m_ < 8; m_++) af[m_] = *(const bf16x8*)(a_ + m_ * 512); \
    _Pragma("unroll") for (int n_ = 0; n_ < 4; n_++) bfr[n_] = *(const bf16x8*)(b_ + n_ * 512); }
#define MM8(mlo) { _Pragma("unroll") for (int m_ = 0; m_ < 4; m_++) \
    { _Pragma("unroll") for (int n_ = 0; n_ < 4; n_++) \
      acc[(mlo) + m_][n_] = __builtin_amdgcn_mfma_f32_16x16x32_bf16(af[(mlo) + m_], bfr[n_], acc[(mlo) + m_][n_], 0, 0, 0); } }
#define PH_MID() __builtin_amdgcn_sched_barrier(0); __builtin_amdgcn_s_barrier(); \
    asm volatile("s_waitcnt lgkmcnt(0)" ::: "memory"); __builtin_amdgcn_sched_barrier(0); \
    __builtin_amdgcn_s_setprio(1)
#define PH_END() __builtin_amdgcn_s_setprio(0); __builtin_amdgcn_sched_barrier(0); \
    __builtin_amdgcn_s_barrier(); __builtin_amdgcn_sched_barrier(0)
#define PH_END_VM(n) __builtin_amdgcn_s_setprio(0); __builtin_amdgcn_sched_barrier(0); \
    asm volatile("s_waitcnt vmcnt(" #n ")" ::: "memory"); \
    __builtin_amdgcn_s_barrier(); __builtin_amdgcn_sched_barrier(0)

__global__ __launch_bounds__(512, 1) void gemm1_8p(
    const u16* __restrict__ hbf, const u16* __restrict__ wiT, size_t wstride,
    const int* __restrict__ slot_token, const int* __restrict__ counts,
    const u16* __restrict__ zerobuf, u16* __restrict__ Hbuf, int p0)
{
    constexpr int KDIM = kD, NTn = kF / 256, NKT = KDIM / 64, NI = NKT / 2;
    int bid = blockIdx.x;
    int nt = bid % NTn;
    int g = bid / NTn;
    int mt = g & 1, pl = g >> 1;
    int pem = p0 + pl;
    int e = pem >> 3, b = pem & 7;
    int pair = b * kE + e;
    int cnt = counts[pair];
    if (mt * 256 >= cnt) return;

    int tid = threadIdx.x, w = tid >> 6, l = tid & 63;
    int wr = w >> 2, wc = w & 3;
    int fr = l & 15, fq = l >> 4;

    extern __shared__ __align__(16) u16 lds[];
    u16* Ap = lds;
    u16* Bp = lds + 32768;
    int* slots = (int*)(lds + 65536);
    if (tid < 256) slots[tid] = slot_token[pair * kC + mt * 256 + tid];
    __syncthreads();

    int r0 = w * 32 + (l >> 2), r1 = r0 + 16;
    int clog = (l & 3) ^ ((l >> 3) & 3);
    int sl0 = slots[r0], sl1 = slots[r1];
    const u16* sA0 = (sl0 >= 0) ? hbf + (size_t)(b * kS + sl0) * kD + clog * 8 : zerobuf + clog * 8;
    const u16* sA1 = (sl1 >= 0) ? hbf + (size_t)(b * kS + sl1) * kD + clog * 8 : zerobuf + clog * 8;
    const u16* wbase = wiT + (size_t)e * wstride;
    const u16* sB0 = wbase + (size_t)(nt * 256 + r0) * KDIM + clog * 8;
    const u16* sB1 = wbase + (size_t)(nt * 256 + r1) * KDIM + clog * 8;
    u16* dA = Ap + w * 1024;
    u16* dB = Bp + w * 1024;

    int sw = (fr >> 1) & 3;
    const u16* rA = Ap + (wr * 128 + fr) * 32 + ((fq ^ sw) << 3);
    const u16* rB = Bp + (wc * 64 + fr) * 32 + ((fq ^ sw) << 3);

    f32x4 acc[8][4];
    #pragma unroll
    for (int m = 0; m < 8; m++)
        #pragma unroll
        for (int n = 0; n < 4; n++) acc[m][n] = (f32x4){0.f, 0.f, 0.f, 0.f};
    bf16x8 af[8], bfr[4];

    SA8(0, 0) SB8(0, 0) SA8(0, 1) SB8(0, 1) SA8(1, 0) SB8(1, 0) SA8(1, 1)
    asm volatile("s_waitcnt vmcnt(6)" ::: "memory");
    __builtin_amdgcn_s_barrier();
    __builtin_amdgcn_sched_barrier(0);

    #pragma unroll 1
    for (int i = 0; i < NI - 1; ++i) {
        int kt0 = 2 * i;
        RD8(0, 0) SB8(kt0 + 1, 1) PH_MID(); MM8(0) PH_END();                 // P1
        SA8(kt0 + 2, 0)           PH_MID(); MM8(4) PH_END();                 // P2
        RD8(0, 1) SB8(kt0 + 2, 0) PH_MID(); MM8(0) PH_END();                 // P3
        SA8(kt0 + 2, 1)           PH_MID(); MM8(4) PH_END_VM(6);             // P4
        RD8(1, 0) SB8(kt0 + 2, 1) PH_MID(); MM8(0) PH_END();                 // P5
        SA8(kt0 + 3, 0)           PH_MID(); MM8(4) PH_END();                 // P6
        RD8(1, 1) SB8(kt0 + 3, 0) PH_MID(); MM8(0) PH_END();                 // P7
        SA8(kt0 + 3, 1)           PH_MID(); MM8(4) PH_END_VM(6);             // P8
    }
    RD8(0, 0) SB8(NKT - 1, 1) PH_MID(); MM8(0) PH_END();
    PH_MID(); MM8(4) PH_END();
    RD8(0, 1) PH_MID(); MM8(0) PH_END();
    PH_MID(); MM8(4) PH_END_VM(0);
    RD8(1, 0) PH_MID(); MM8(0) PH_END();
    PH_MID(); MM8(4) PH_END();
    RD8(1, 1) PH_MID(); MM8(0) PH_END();
    PH_MID(); MM8(4) __builtin_amdgcn_s_setprio(0); __builtin_amdgcn_sched_barrier(0);

    size_t hbase = (size_t)pl * kC * kF;
    int rbase = mt * 256 + wr * 128, c0 = nt * 256 + wc * 64;
    #pragma unroll
    for (int m = 0; m < 8; m++) {
        #pragma unroll
        for (int j = 0; j < 4; j++) {
            int row = rbase + m * 16 + fq * 4 + j;
            size_t rb = hbase + (size_t)row * kF;
            #pragma unroll
            for (int n = 0; n < 4; n++)
                Hbuf[rb + c0 + n * 16 + fr] = f2bf(fmaxf(acc[m][n][j], 0.f));
        }
    }
}

__global__ __launch_bounds__(512, 1) void gemm2_8p(
    const u16* __restrict__ Hbuf, const u16* __restrict__ woT, size_t wstride,
    const int* __restrict__ slot_token, const int* __restrict__ counts,
    const float* __restrict__ maxprob, float* __restrict__ outp, int p0)
{
    constexpr int KDIM = kF, NTn = kD / 256, NKT = KDIM / 64, NI = NKT / 2;
    int bid = blockIdx.x;
    int nt = bid % NTn;
    int g = bid / NTn;
    int mt = g & 1, pl = g >> 1;
    int pem = p0 + pl;
    int e = pem >> 3, b = pem & 7;
    int pair = b * kE + e;
    int cnt = counts[pair];
    if (mt * 256 >= cnt) return;

    int tid = threadIdx.x, w = tid >> 6, l = tid & 63;
    int wr = w >> 2, wc = w & 3;
    int fr = l & 15, fq = l >> 4;

    extern __shared__ __align__(16) u16 lds[];
    u16* Ap = lds;
    u16* Bp = lds + 32768;
    int* slots = (int*)(lds + 65536);
    if (tid < 256) slots[tid] = slot_token[pair * kC + mt * 256 + tid];
    __syncthreads();

    int r0 = w * 32 + (l >> 2), r1 = r0 + 16;
    int clog = (l & 3) ^ ((l >> 3) & 3);
    const u16* sA0 = Hbuf + ((size_t)pl * kC + mt * 256 + r0) * kF + clog * 8;
    const u16* sA1 = Hbuf + ((size_t)pl * kC + mt * 256 + r1) * kF + clog * 8;
    const u16* wbase = woT + (size_t)e * wstride;
    const u16* sB0 = wbase + (size_t)(nt * 256 + r0) * KDIM + clog * 8;
    const u16* sB1 = wbase + (size_t)(nt * 256 + r1) * KDIM + clog * 8;
    u16* dA = Ap + w * 1024;
    u16* dB = Bp + w * 1024;

    int sw = (fr >> 1) & 3;
    const u16* rA = Ap + (wr * 128 + fr) * 32 + ((fq ^ sw) << 3);
    const u16* rB = Bp + (wc * 64 + fr) * 32 + ((fq ^ sw) << 3);

    f32x4 acc[8][4];
    #pragma unroll
    for (int m = 0; m < 8; m++)
        #pragma unroll
        for (int n = 0; n < 4; n++) acc[m][n] = (f32x4){0.f, 0.f, 0.f, 0.f};
    bf16x8 af[8], bfr[4];

    SA8(0, 0) SB8(0, 0) SA8(0, 1) SB8(0, 1) SA8(1, 0) SB8(1, 0) SA8(1, 1)
    asm volatile("s_waitcnt vmcnt(6)" ::: "memory");
    __builtin_amdgcn_s_barrier();
    __builtin_amdgcn_sched_barrier(0);

    #pragma unroll 1
    for (int i = 0; i < NI - 1; ++i) {
        int kt0 = 2 * i;
        RD8(0, 0) SB8(kt0 + 1, 1) PH_MID(); MM8(0) PH_END();
        SA8(kt0 + 2, 0)           PH_MID(); MM8(4) PH_END();
        RD8(0, 1) SB8(kt0 + 2, 0) PH_MID(); MM8(0) PH_END();
        SA8(kt0 + 2, 1)           PH_MID(); MM8(4) PH_END_VM(6);
        RD8(1, 0) SB8(kt0 + 2, 1) PH_MID(); MM8(0) PH_END();
        SA8(kt0 + 3, 0)           PH_MID(); MM8(4) PH_END();
        RD8(1, 1) SB8(kt0 + 3, 0) PH_MID(); MM8(0) PH_END();
        SA8(kt0 + 3, 1)           PH_MID(); MM8(4) PH_END_VM(6);
    }
    RD8(0, 0) SB8(NKT - 1, 1) PH_MID(); MM8(0) PH_END();
    PH_MID(); MM8(4) PH_END();
    RD8(0, 1) PH_MID(); MM8(0) PH_END();
    PH_MID(); MM8(4) PH_END_VM(0);
    RD8(1, 0) PH_MID(); MM8(0) PH_END();
    PH_MID(); MM8(4) PH_END();
    RD8(1, 1) PH_MID(); MM8(0) PH_END();
    PH_MID(); MM8(4) __builtin_amdgcn_s_setprio(0); __builtin_amdgcn_sched_barrier(0);

    int c0 = nt * 256 + wc * 64;
    #pragma unroll
    for (int m = 0; m < 8; m++) {
        #pragma unroll
        for (int j = 0; j < 4; j++) {
            int rl = wr * 128 + m * 16 + fq * 4 + j;
            int s = slots[rl];
            if (s >= 0) {
                float p = maxprob[b * kS + s];
                size_t ob = (size_t)(b * kS + s) * kD;
                #pragma unroll
                for (int n = 0; n < 4; n++)
                    outp[ob + c0 + n * 16 + fr] = acc[m][n][j] * p;
            }
        }
    }
}

#undef SA8
#undef SB8
#undef RD8
#undef MM8
#undef PH_MID
#undef PH_END
#undef PH_END_VM

// ---------------- naive fp32 fallback (proven) ----------------
__global__ __launch_bounds__(256) void ngemm1_k(
    const float* __restrict__ hidden, const float* __restrict__ wi,
    const int* __restrict__ slot_token, const int* __restrict__ counts,
    float* __restrict__ H, int pair)
{
    int b = pair >> 3, e = pair & 7;
    int cnt = counts[pair];
    int c0 = blockIdx.y * 64, f0 = blockIdx.x * 64;
    if (c0 >= cnt) return;
    __shared__ float As[64][17];
    __shared__ float Bs[16][65];
    __shared__ int slots[64];
    int tx = threadIdx.x, ty = threadIdx.y;
    int tid = ty * 16 + tx;
    if (tid < 64) slots[tid] = slot_token[pair * kC + c0 + tid];
    __syncthreads();
    float acc[4][4];
    #pragma unroll
    for (int i = 0; i < 4; i++)
        #pragma unroll
        for (int j = 0; j < 4; j++) acc[i][j] = 0.f;
    int ar = tid >> 2, ak = (tid & 3) * 4;
    int bd = tid >> 4, bf = (tid & 15) * 4;
    const float* wie = wi + (size_t)e * kD * kF;
    for (int k0 = 0; k0 < kD; k0 += 16) {
        int sl = slots[ar];
        if (sl >= 0) {
            float4 v = *(const float4*)(hidden + (size_t)(b * kS + sl) * kD + k0 + ak);
            As[ar][ak] = v.x; As[ar][ak + 1] = v.y; As[ar][ak + 2] = v.z; As[ar][ak + 3] = v.w;
        } else {
            As[ar][ak] = 0.f; As[ar][ak + 1] = 0.f; As[ar][ak + 2] = 0.f; As[ar][ak + 3] = 0.f;
        }
        float4 wv = *(const float4*)(wie + (size_t)(k0 + bd) * kF + f0 + bf);
        Bs[bd][bf] = wv.x; Bs[bd][bf + 1] = wv.y; Bs[bd][bf + 2] = wv.z; Bs[bd][bf + 3] = wv.w;
        __syncthreads();
        #pragma unroll
        for (int kk = 0; kk < 16; kk++) {
            float a[4], bv[4];
            #pragma unroll
            for (int i = 0; i < 4; i++) a[i] = As[ty * 4 + i][kk];
            #pragma unroll
            for (int j = 0; j < 4; j++) bv[j] = Bs[kk][tx * 4 + j];
            #pragma unroll
            for (int i = 0; i < 4; i++)
                #pragma unroll
                for (int j = 0; j < 4; j++) acc[i][j] += a[i] * bv[j];
        }
        __syncthreads();
    }
    #pragma unroll
    for (int i = 0; i < 4; i++) {
        int row = c0 + ty * 4 + i;
        #pragma unroll
        for (int j = 0; j < 4; j++)
            H[(size_t)row * kF + f0 + tx * 4 + j] = fmaxf(acc[i][j], 0.f);
    }
}

__global__ __launch_bounds__(256) void ngemm2_k(
    const float* __restrict__ H, const float* __restrict__ wo,
    const int* __restrict__ slot_token, const int* __restrict__ counts,
    const float* __restrict__ maxprob, float* __restrict__ outp, int pair)
{
    int b = pair >> 3, e = pair & 7;
    int cnt = counts[pair];
    int c0 = blockIdx.y * 64, d0 = blockIdx.x * 64;
    if (c0 >= cnt) return;
    __shared__ float As[64][17];
    __shared__ float Bs[16][65];
    __shared__ int slots[64];
    int tx = threadIdx.x, ty = threadIdx.y;
    int tid = ty * 16 + tx;
    if (tid < 64) slots[tid] = slot_token[pair * kC + c0 + tid];
    __syncthreads();
    float acc[4][4];
    #pragma unroll
    for (int i = 0; i < 4; i++)
        #pragma unroll
        for (int j = 0; j < 4; j++) acc[i][j] = 0.f;
    int ar = tid >> 2, ak = (tid & 3) * 4;
    int bd = tid >> 4, bf = (tid & 15) * 4;
    const float* woe = wo + (size_t)e * kF * kD;
    for (int k0 = 0; k0 < kF; k0 += 16) {
        float4 v = *(const float4*)(H + (size_t)(c0 + ar) * kF + k0 + ak);
        As[ar][ak] = v.x; As[ar][ak + 1] = v.y; As[ar][ak + 2] = v.z; As[ar][ak + 3] = v.w;
        float4 wv = *(const float4*)(woe + (size_t)(k0 + bd) * kD + d0 + bf);
        Bs[bd][bf] = wv.x; Bs[bd][bf + 1] = wv.y; Bs[bd][bf + 2] = wv.z; Bs[bd][bf + 3] = wv.w;
        __syncthreads();
        #pragma unroll
        for (int kk = 0; kk < 16; kk++) {
            float a[4], bv[4];
            #pragma unroll
            for (int i = 0; i < 4; i++) a[i] = As[ty * 4 + i][kk];
            #pragma unroll
            for (int j = 0; j < 4; j++) bv[j] = Bs[kk][tx * 4 + j];
            #pragma unroll
            for (int i = 0; i < 4; i++)
                #pragma unroll
                for (int j = 0; j < 4; j++) acc[i][j] += a[i] * bv[j];
        }
        __syncthreads();
    }
    #pragma unroll
    for (int i = 0; i < 4; i++) {
        int s = slots[ty * 4 + i];
        if (s >= 0) {
            float p = maxprob[b * kS + s];
            size_t ob = (size_t)(b * kS + s) * kD;
            #pragma unroll
            for (int j = 0; j < 4; j++)
                outp[ob + d0 + tx * 4 + j] = acc[i][j] * p;
        }
    }
}

extern "C" void kernel_launch(void* const* d_in, const int* in_sizes, int n_in,
                              void* d_out, int out_size, void* d_ws, size_t ws_size,
                              hipStream_t stream)
{
    const float* hidden = (const float*)d_in[0];
    const float* rw     = (const float*)d_in[1];
    const float* wi     = (const float*)d_in[2];
    const float* wo     = (const float*)d_in[3];
    float* outp   = (float*)d_out;
    float* logits = outp + (size_t)kB * kS * kD;
    float* expidx = logits + (size_t)kB * kS * kE;

    char* ws = (char*)d_ws;
    size_t off = 0;
    auto alloc = [&](size_t bytes) -> char* {
        char* p = ws + off; off += (bytes + 255) & ~(size_t)255; return p;
    };
    int*   slot_token = (int*)  alloc((size_t)kB * kE * kC * 4);
    int*   counts     = (int*)  alloc((size_t)kB * kE * 4);
    int*   expert_id  = (int*)  alloc((size_t)kB * kS * 4);
    float* maxprob    = (float*)alloc((size_t)kB * kS * 4);
    size_t small_off = off;

    const size_t wsz   = (size_t)kD * kF * 2;       // 8 MiB per expert, bf16
    const size_t hsz   = (size_t)kC * kF * 2;       // 4 MiB per pair, bf16
    const size_t hbfsz = (size_t)kB * kS * kD * 2;  // 32 MiB bf16 hidden image

    hipFuncSetAttribute(reinterpret_cast<const void*>(gemm1_8p),
                        hipFuncAttributeMaxDynamicSharedMemorySize, kSmemBytes);
    hipFuncSetAttribute(reinterpret_cast<const void*>(gemm2_8p),
                        hipFuncAttributeMaxDynamicSharedMemorySize, kSmemBytes);

    bool tierA = ws_size >= small_off + 2 * kE * wsz + hbfsz + 4096 + 4 * hsz;
    bool tierB = !tierA && ws_size >= small_off + 2 * wsz + hbfsz + 4096 + hsz;

    if (tierA) {
        u16* wiT = (u16*)alloc(kE * wsz);   // 64 MiB
        u16* woT = (u16*)alloc(kE * wsz);   // 64 MiB
        u16* hbf = (u16*)alloc(hbfsz);      // 32 MiB
        u16* zerobuf = (u16*)alloc(4096);
        int Gb = (int)((ws_size - off) / hsz);
        if (Gb > kB * kE) Gb = kB * kE;
        if (Gb < 1) Gb = 1;
        u16* Hbuf = (u16*)alloc((size_t)Gb * hsz);

        init_k<<<2048, 256, 0, stream>>>((uint4*)outp, (uint4*)zerobuf);
        router_k<<<kB * kS / 4, 256, 0, stream>>>(hidden, rw, logits, expert_id, maxprob, hbf);
        scan_k<<<kB, 64, 0, stream>>>(expert_id, slot_token, counts, expidx);
        transpose_v<<<dim3(kF / 64, kD / 64, kE), 256, 0, stream>>>(wi, wiT, kD, kF);
        transpose_v<<<dim3(kD / 64, kF / 64, kE), 256, 0, stream>>>(wo, woT, kF, kD);
        for (int p0 = 0; p0 < kB * kE; p0 += Gb) {
            int g = kB * kE - p0 < Gb ? kB * kE - p0 : Gb;
            gemm1_8p<<<g * 2 * (kF / 256), 512, kSmemBytes, stream>>>(
                hbf, wiT, (size_t)kD * kF, slot_token, counts, zerobuf, Hbuf, p0);
            gemm2_8p<<<g * 2 * (kD / 256), 512, kSmemBytes, stream>>>(
                Hbuf, woT, (size_t)kD * kF, slot_token, counts, maxprob, outp, p0);
        }
    } else if (tierB) {
        u16* wiT = (u16*)alloc(wsz);
        u16* woT = (u16*)alloc(wsz);
        u16* hbf = (u16*)alloc(hbfsz);
        u16* zerobuf = (u16*)alloc(4096);
        int Gb = (int)((ws_size - off) / hsz);
        if (Gb > kB) Gb = kB;
        if (Gb < 1) Gb = 1;
        u16* Hbuf = (u16*)alloc((size_t)Gb * hsz);

        init_k<<<2048, 256, 0, stream>>>((uint4*)outp, (uint4*)zerobuf);
        router_k<<<kB * kS / 4, 256, 0, stream>>>(hidden, rw, logits, expert_id, maxprob, hbf);
        scan_k<<<kB, 64, 0, stream>>>(expert_id, slot_token, counts, expidx);
        for (int e = 0; e < kE; e++) {
            transpose_v<<<dim3(kF / 64, kD / 64, 1), 256, 0, stream>>>(
                wi + (size_t)e * kD * kF, wiT, kD, kF);
            transpose_v<<<dim3(kD / 64, kF / 64, 1), 256, 0, stream>>>(
                wo + (size_t)e * kD * kF, woT, kF, kD);
            for (int b0 = 0; b0 < kB; b0 += Gb) {
                int g = kB - b0 < Gb ? kB - b0 : Gb;
                int p0 = e * 8 + b0;
                gemm1_8p<<<g * 2 * (kF / 256), 512, kSmemBytes, stream>>>(
                    hbf, wiT, 0, slot_token, counts, zerobuf, Hbuf, p0);
                gemm2_8p<<<g * 2 * (kD / 256), 512, kSmemBytes, stream>>>(
                    Hbuf, woT, 0, slot_token, counts, maxprob, outp, p0);
            }
        }
    } else {
        float* H = (float*)alloc((size_t)kC * kF * 4);
        init_k<<<2048, 256, 0, stream>>>((uint4*)outp, nullptr);
        router_k<<<kB * kS / 4, 256, 0, stream>>>(hidden, rw, logits, expert_id, maxprob, nullptr);
        scan_k<<<kB, 64, 0, stream>>>(expert_id, slot_token, counts, expidx);
        for (int pair = 0; pair < kB * kE; pair++) {
            ngemm1_k<<<dim3(kF / 64, kC / 64), dim3(16, 16), 0, stream>>>(
                hidden, wi, slot_token, counts, H, pair);
            ngemm2_k<<<dim3(kD / 64, kC / 64), dim3(16, 16), 0, stream>>>(
                H, wo, slot_token, counts, maxprob, outp, pair);
        }
    }
}

// Round 14
// 833.316 us; speedup vs baseline: 1.3973x; 1.0451x over previous
//
#include <hip/hip_runtime.h>
#include <stdint.h>

static constexpr int kB = 8, kS = 2048, kD = 1024, kF = 4096, kE = 8, kC = 512;

typedef unsigned short u16;
typedef __attribute__((ext_vector_type(8))) short bf16x8;
typedef __attribute__((ext_vector_type(4))) float f32x4;

__device__ __forceinline__ u16 f2bf(float f) {
    union { float f; uint32_t u; } v; v.f = f;
    return (u16)((v.u + 0x7fffu + ((v.u >> 16) & 1u)) >> 16);
}
__device__ __forceinline__ void gload16(const u16* g, u16* l) {
    __builtin_amdgcn_global_load_lds(
        (__attribute__((address_space(1))) void*)(u16*)g,
        (__attribute__((address_space(3))) void*)l, 16, 0, 0);
}

static constexpr int kSmemBytes = 132096;  // A 64KB + B 64KB + slots 1KB

// ---------------- init: zero the fp32 `out` region of d_out + zero page ----------------
__global__ void init_k(uint4* __restrict__ outz, uint4* __restrict__ zb) {
    if (blockIdx.x == 0 && zb && threadIdx.x < 256) zb[threadIdx.x] = (uint4){0, 0, 0, 0};
    const size_t n = (size_t)kB * kS * kD * 4 / 16;
    size_t stride = (size_t)gridDim.x * blockDim.x;
    for (size_t i = (size_t)blockIdx.x * blockDim.x + threadIdx.x; i < n; i += stride)
        outz[i] = (uint4){0, 0, 0, 0};
}

// ---------------- router (fused): fp32 logits + argmax + writes bf16 hidden image ----------
__global__ __launch_bounds__(256) void router_k(
    const float* __restrict__ hidden, const float* __restrict__ rw,
    float* __restrict__ logits_out, int* __restrict__ expert_id, float* __restrict__ maxprob,
    u16* __restrict__ hbf)
{
    int token = blockIdx.x * 4 + (threadIdx.x >> 6);
    int lane = threadIdx.x & 63;
    const float* hrow = hidden + (size_t)token * kD;
    float acc[8] = {0, 0, 0, 0, 0, 0, 0, 0};
    for (int d0 = lane * 4; d0 < kD; d0 += 256) {
        float4 h4 = *(const float4*)(hrow + d0);
        float hv[4] = {h4.x, h4.y, h4.z, h4.w};
        if (hbf) {
            u16 t4[4] = {f2bf(h4.x), f2bf(h4.y), f2bf(h4.z), f2bf(h4.w)};
            *(uint2*)(hbf + (size_t)token * kD + d0) = *(const uint2*)t4;
        }
        #pragma unroll
        for (int j = 0; j < 4; j++) {
            const float* wr = rw + (size_t)(d0 + j) * 8;
            float4 w0 = *(const float4*)wr, w1 = *(const float4*)(wr + 4);
            acc[0] += hv[j] * w0.x; acc[1] += hv[j] * w0.y;
            acc[2] += hv[j] * w0.z; acc[3] += hv[j] * w0.w;
            acc[4] += hv[j] * w1.x; acc[5] += hv[j] * w1.y;
            acc[6] += hv[j] * w1.z; acc[7] += hv[j] * w1.w;
        }
    }
    #pragma unroll
    for (int off = 32; off >= 1; off >>= 1) {
        #pragma unroll
        for (int e = 0; e < 8; e++) acc[e] += __shfl_down(acc[e], off, 64);
    }
    if (lane == 0) {
        float m = acc[0];
        #pragma unroll
        for (int e = 1; e < 8; e++) m = fmaxf(m, acc[e]);
        float ex[8], s = 0.f;
        #pragma unroll
        for (int e = 0; e < 8; e++) { ex[e] = expf(acc[e] - m); s += ex[e]; }
        int best = 0; float bv = -1.f;
        #pragma unroll
        for (int e = 0; e < 8; e++) {
            float p = ex[e] / s;
            if (p > bv) { bv = p; best = e; }
            logits_out[(size_t)token * 8 + e] = acc[e];
        }
        expert_id[token] = best;
        maxprob[token] = bv;
    }
}

// ---------------- capacity scan (proven) ----------------
__global__ __launch_bounds__(64) void scan_k(
    const int* __restrict__ expert_id, int* __restrict__ slot_token,
    int* __restrict__ counts, float* __restrict__ expidx_out)
{
    __shared__ int eids[kS];
    int b = blockIdx.x, tid = threadIdx.x;
    for (int s = tid; s < kS; s += 64) eids[s] = expert_id[b * kS + s];
    __syncthreads();
    if (tid < kE) {
        int e = tid, cnt = 0;
        for (int s = 0; s < kS; s++) {
            if (eids[s] == e) {
                if (cnt < kC) {
                    slot_token[(b * kE + e) * kC + cnt] = s;
                    expidx_out[b * kS + s] = (float)e;
                    cnt++;
                } else {
                    expidx_out[b * kS + s] = 0.f;
                }
            }
        }
        counts[b * kE + e] = cnt;
        for (int c = cnt; c < kC; c++) slot_token[(b * kE + e) * kC + c] = -1;
    }
}

// ---------------- vectorized convert-transpose: fp32 [R][Cn] -> bf16 [Cn][R] ----------------
__global__ __launch_bounds__(256) void transpose_v(
    const float* __restrict__ src, u16* __restrict__ dst, int R, int Cn)
{
    __shared__ u16 tl[64][68];
    size_t eo = (size_t)blockIdx.z * R * Cn;
    int c0 = blockIdx.x * 64, r0 = blockIdx.y * 64;
    int t = threadIdx.x;
    int tx = t & 15, ty = t >> 4;
    #pragma unroll
    for (int i = 0; i < 4; i++) {
        int r = ty + 16 * i;
        float4 v = *(const float4*)(src + eo + (size_t)(r0 + r) * Cn + c0 + tx * 4);
        tl[tx * 4 + 0][r] = f2bf(v.x);
        tl[tx * 4 + 1][r] = f2bf(v.y);
        tl[tx * 4 + 2][r] = f2bf(v.z);
        tl[tx * 4 + 3][r] = f2bf(v.w);
    }
    __syncthreads();
    int seg = t & 7, clb = t >> 3;
    #pragma unroll
    for (int ii = 0; ii < 2; ii++) {
        int cl = clb + 32 * ii;
        uint4 v = *(const uint4*)&tl[cl][seg * 8];
        *(uint4*)(dst + eo + (size_t)(c0 + cl) * R + r0 + seg * 8) = v;
    }
}

// ================= 8-phase 256x256 MFMA GEMM, persistent work-loop =================
#define SA8(kt, kh) { int off_ = (((kt) & 1) << 14) + ((kh) << 13); int go_ = (kt) * 64 + (kh) * 32; \
    gload16(sA0 + go_, dA + off_); gload16(sA1 + go_, dA + off_ + 512); }
#define SB8(kt, kh) { int off_ = (((kt) & 1) << 14) + ((kh) << 13); int go_ = (kt) * 64 + (kh) * 32; \
    gload16(sB0 + go_, dB + off_); gload16(sB1 + go_, dB + off_ + 512); }
#define RD8(buf, kh) { const u16* a_ = rA + ((buf) << 14) + ((kh) << 13); \
    const u16* b_ = rB + ((buf) << 14) + ((kh) << 13); \
    _Pragma("unroll") for (int m_ = 0; m_ < 8; m_++) af[m_] = *(const bf16x8*)(a_ + m_ * 512); \
    _Pragma("unroll") for (int n_ = 0; n_ < 4; n_++) bfr[n_] = *(const bf16x8*)(b_ + n_ * 512); }
#define MM8(mlo) { _Pragma("unroll") for (int m_ = 0; m_ < 4; m_++) \
    { _Pragma("unroll") for (int n_ = 0; n_ < 4; n_++) \
      acc[(mlo) + m_][n_] = __builtin_amdgcn_mfma_f32_16x16x32_bf16(af[(mlo) + m_], bfr[n_], acc[(mlo) + m_][n_], 0, 0, 0); } }
#define PH_MID() __builtin_amdgcn_sched_barrier(0); __builtin_amdgcn_s_barrier(); \
    asm volatile("s_waitcnt lgkmcnt(0)" ::: "memory"); __builtin_amdgcn_sched_barrier(0); \
    __builtin_amdgcn_s_setprio(1)
#define PH_END() __builtin_amdgcn_s_setprio(0); __builtin_amdgcn_sched_barrier(0); \
    __builtin_amdgcn_s_barrier(); __builtin_amdgcn_sched_barrier(0)
#define PH_END_VM(n) __builtin_amdgcn_s_setprio(0); __builtin_amdgcn_sched_barrier(0); \
    asm volatile("s_waitcnt vmcnt(" #n ")" ::: "memory"); \
    __builtin_amdgcn_s_barrier(); __builtin_amdgcn_sched_barrier(0)

// ---------------- GEMM1 (8-phase, persistent): H = relu(gather(hbf) @ wiT^T) ----------------
__global__ __launch_bounds__(512, 1) void gemm1_8p(
    const u16* __restrict__ hbf, const u16* __restrict__ wiT, size_t wstride,
    const int* __restrict__ slot_token, const int* __restrict__ counts,
    const u16* __restrict__ zerobuf, u16* __restrict__ Hbuf,
    int p0, int nItems, int full)
{
    constexpr int KDIM = kD, NTn = kF / 256, NKT = KDIM / 64, NI = NKT / 2;
    int tid = threadIdx.x, w = tid >> 6, l = tid & 63;
    int wr = w >> 2, wc = w & 3;
    int fr = l & 15, fq = l >> 4;
    int r0 = w * 32 + (l >> 2), r1 = r0 + 16;
    int clog = (l & 3) ^ ((l >> 3) & 3);
    int sw = (fr >> 1) & 3;

    extern __shared__ __align__(16) u16 lds[];
    u16* Ap = lds;
    u16* Bp = lds + 32768;
    int* slots = (int*)(lds + 65536);
    u16* dA = Ap + w * 1024;
    u16* dB = Bp + w * 1024;
    const u16* rA = Ap + (wr * 128 + fr) * 32 + ((fq ^ sw) << 3);
    const u16* rB = Bp + (wc * 64 + fr) * 32 + ((fq ^ sw) << 3);
    int nblk = gridDim.x;

    #pragma unroll 1
    for (int it = 0; blockIdx.x + it * nblk < nItems; ++it) {
        int pem, mt, nt;
        if (full) {
            // B-affinity decode: slot fixes (e, nt); rounds walk (b, mt)
            int ent = blockIdx.x >> 1, par = blockIdx.x & 1;
            int e_ = ent >> 4;
            nt = ent & 15;
            mt = (it & 1) ^ par;
            pem = e_ * 8 + it;
        } else {
            int i = blockIdx.x + it * nblk;
            nt = i % NTn;
            int g = i / NTn;
            mt = g & 1;
            pem = p0 + (g >> 1);
        }
        int e = pem >> 3, b = pem & 7;
        int pair = b * kE + e;
        int pl = pem - p0;
        int cnt = counts[pair];
        if (mt * 256 >= cnt) continue;

        if (tid < 256) slots[tid] = slot_token[pair * kC + mt * 256 + tid];
        __syncthreads();

        int sl0 = slots[r0], sl1 = slots[r1];
        const u16* sA0 = (sl0 >= 0) ? hbf + (size_t)(b * kS + sl0) * kD + clog * 8 : zerobuf + clog * 8;
        const u16* sA1 = (sl1 >= 0) ? hbf + (size_t)(b * kS + sl1) * kD + clog * 8 : zerobuf + clog * 8;
        const u16* wbase = wiT + (size_t)e * wstride;
        const u16* sB0 = wbase + (size_t)(nt * 256 + r0) * KDIM + clog * 8;
        const u16* sB1 = wbase + (size_t)(nt * 256 + r1) * KDIM + clog * 8;

        f32x4 acc[8][4];
        #pragma unroll
        for (int m = 0; m < 8; m++)
            #pragma unroll
            for (int n = 0; n < 4; n++) acc[m][n] = (f32x4){0.f, 0.f, 0.f, 0.f};
        bf16x8 af[8], bfr[4];

        SA8(0, 0) SB8(0, 0) SA8(0, 1) SB8(0, 1) SA8(1, 0) SB8(1, 0) SA8(1, 1)
        asm volatile("s_waitcnt vmcnt(6)" ::: "memory");
        __builtin_amdgcn_s_barrier();
        __builtin_amdgcn_sched_barrier(0);

        #pragma unroll 1
        for (int i2 = 0; i2 < NI - 1; ++i2) {
            int kt0 = 2 * i2;
            RD8(0, 0) SB8(kt0 + 1, 1) PH_MID(); MM8(0) PH_END();
            SA8(kt0 + 2, 0)           PH_MID(); MM8(4) PH_END();
            RD8(0, 1) SB8(kt0 + 2, 0) PH_MID(); MM8(0) PH_END();
            SA8(kt0 + 2, 1)           PH_MID(); MM8(4) PH_END_VM(6);
            RD8(1, 0) SB8(kt0 + 2, 1) PH_MID(); MM8(0) PH_END();
            SA8(kt0 + 3, 0)           PH_MID(); MM8(4) PH_END();
            RD8(1, 1) SB8(kt0 + 3, 0) PH_MID(); MM8(0) PH_END();
            SA8(kt0 + 3, 1)           PH_MID(); MM8(4) PH_END_VM(6);
        }
        RD8(0, 0) SB8(NKT - 1, 1) PH_MID(); MM8(0) PH_END();
        PH_MID(); MM8(4) PH_END();
        RD8(0, 1) PH_MID(); MM8(0) PH_END();
        PH_MID(); MM8(4) PH_END_VM(0);
        RD8(1, 0) PH_MID(); MM8(0) PH_END();
        PH_MID(); MM8(4) PH_END();
        RD8(1, 1) PH_MID(); MM8(0) PH_END();
        PH_MID(); MM8(4) __builtin_amdgcn_s_setprio(0); __builtin_amdgcn_sched_barrier(0);

        size_t hbase = (size_t)pl * kC * kF;
        int rbase = mt * 256 + wr * 128, c0 = nt * 256 + wc * 64;
        #pragma unroll
        for (int m = 0; m < 8; m++) {
            #pragma unroll
            for (int j = 0; j < 4; j++) {
                int row = rbase + m * 16 + fq * 4 + j;
                size_t rb = hbase + (size_t)row * kF;
                #pragma unroll
                for (int n = 0; n < 4; n++)
                    Hbuf[rb + c0 + n * 16 + fr] = f2bf(fmaxf(acc[m][n][j], 0.f));
            }
        }
        __syncthreads();   // protect slots[] before next item
    }
}

// ---------------- GEMM2 (8-phase, persistent): out = (H @ woT^T) * max_prob ----------------
__global__ __launch_bounds__(512, 1) void gemm2_8p(
    const u16* __restrict__ Hbuf, const u16* __restrict__ woT, size_t wstride,
    const int* __restrict__ slot_token, const int* __restrict__ counts,
    const float* __restrict__ maxprob, float* __restrict__ outp,
    int p0, int nItems, int full)
{
    constexpr int KDIM = kF, NTn = kD / 256, NKT = KDIM / 64, NI = NKT / 2;
    int tid = threadIdx.x, w = tid >> 6, l = tid & 63;
    int wr = w >> 2, wc = w & 3;
    int fr = l & 15, fq = l >> 4;
    int r0 = w * 32 + (l >> 2), r1 = r0 + 16;
    int clog = (l & 3) ^ ((l >> 3) & 3);
    int sw = (fr >> 1) & 3;

    extern __shared__ __align__(16) u16 lds[];
    u16* Ap = lds;
    u16* Bp = lds + 32768;
    int* slots = (int*)(lds + 65536);
    u16* dA = Ap + w * 1024;
    u16* dB = Bp + w * 1024;
    const u16* rA = Ap + (wr * 128 + fr) * 32 + ((fq ^ sw) << 3);
    const u16* rB = Bp + (wc * 64 + fr) * 32 + ((fq ^ sw) << 3);
    int nblk = gridDim.x;

    #pragma unroll 1
    for (int it = 0; blockIdx.x + it * nblk < nItems; ++it) {
        int pem, mt, nt;
        if (full) {
            // slot = ((e*4+nt)*2+par)*4 + bq ; rounds walk (r): b=bq*2+r, mt=r^par
            int bq = blockIdx.x & 3;
            int t2 = blockIdx.x >> 2;
            int par = t2 & 1;
            int ent = t2 >> 1;           // [0,32)
            int e_ = ent >> 2;
            nt = ent & 3;
            int b_ = bq * 2 + it;
            mt = (it & 1) ^ par;
            pem = e_ * 8 + b_;
        } else {
            int i = blockIdx.x + it * nblk;
            nt = i % NTn;
            int g = i / NTn;
            mt = g & 1;
            pem = p0 + (g >> 1);
        }
        int e = pem >> 3, b = pem & 7;
        int pair = b * kE + e;
        int pl = pem - p0;
        int cnt = counts[pair];
        if (mt * 256 >= cnt) continue;

        if (tid < 256) slots[tid] = slot_token[pair * kC + mt * 256 + tid];
        __syncthreads();

        const u16* sA0 = Hbuf + ((size_t)pl * kC + mt * 256 + r0) * kF + clog * 8;
        const u16* sA1 = Hbuf + ((size_t)pl * kC + mt * 256 + r1) * kF + clog * 8;
        const u16* wbase = woT + (size_t)e * wstride;
        const u16* sB0 = wbase + (size_t)(nt * 256 + r0) * KDIM + clog * 8;
        const u16* sB1 = wbase + (size_t)(nt * 256 + r1) * KDIM + clog * 8;

        f32x4 acc[8][4];
        #pragma unroll
        for (int m = 0; m < 8; m++)
            #pragma unroll
            for (int n = 0; n < 4; n++) acc[m][n] = (f32x4){0.f, 0.f, 0.f, 0.f};
        bf16x8 af[8], bfr[4];

        SA8(0, 0) SB8(0, 0) SA8(0, 1) SB8(0, 1) SA8(1, 0) SB8(1, 0) SA8(1, 1)
        asm volatile("s_waitcnt vmcnt(6)" ::: "memory");
        __builtin_amdgcn_s_barrier();
        __builtin_amdgcn_sched_barrier(0);

        #pragma unroll 1
        for (int i2 = 0; i2 < NI - 1; ++i2) {
            int kt0 = 2 * i2;
            RD8(0, 0) SB8(kt0 + 1, 1) PH_MID(); MM8(0) PH_END();
            SA8(kt0 + 2, 0)           PH_MID(); MM8(4) PH_END();
            RD8(0, 1) SB8(kt0 + 2, 0) PH_MID(); MM8(0) PH_END();
            SA8(kt0 + 2, 1)           PH_MID(); MM8(4) PH_END_VM(6);
            RD8(1, 0) SB8(kt0 + 2, 1) PH_MID(); MM8(0) PH_END();
            SA8(kt0 + 3, 0)           PH_MID(); MM8(4) PH_END();
            RD8(1, 1) SB8(kt0 + 3, 0) PH_MID(); MM8(0) PH_END();
            SA8(kt0 + 3, 1)           PH_MID(); MM8(4) PH_END_VM(6);
        }
        RD8(0, 0) SB8(NKT - 1, 1) PH_MID(); MM8(0) PH_END();
        PH_MID(); MM8(4) PH_END();
        RD8(0, 1) PH_MID(); MM8(0) PH_END();
        PH_MID(); MM8(4) PH_END_VM(0);
        RD8(1, 0) PH_MID(); MM8(0) PH_END();
        PH_MID(); MM8(4) PH_END();
        RD8(1, 1) PH_MID(); MM8(0) PH_END();
        PH_MID(); MM8(4) __builtin_amdgcn_s_setprio(0); __builtin_amdgcn_sched_barrier(0);

        int c0 = nt * 256 + wc * 64;
        #pragma unroll
        for (int m = 0; m < 8; m++) {
            #pragma unroll
            for (int j = 0; j < 4; j++) {
                int rl = wr * 128 + m * 16 + fq * 4 + j;
                int s = slots[rl];
                if (s >= 0) {
                    float p = maxprob[b * kS + s];
                    size_t ob = (size_t)(b * kS + s) * kD;
                    #pragma unroll
                    for (int n = 0; n < 4; n++)
                        outp[ob + c0 + n * 16 + fr] = acc[m][n][j] * p;
                }
            }
        }
        __syncthreads();   // protect slots[] before next item
    }
}

#undef SA8
#undef SB8
#undef RD8
#undef MM8
#undef PH_MID
#undef PH_END
#undef PH_END_VM

// ---------------- naive fp32 fallback (proven) ----------------
__global__ __launch_bounds__(256) void ngemm1_k(
    const float* __restrict__ hidden, const float* __restrict__ wi,
    const int* __restrict__ slot_token, const int* __restrict__ counts,
    float* __restrict__ H, int pair)
{
    int b = pair >> 3, e = pair & 7;
    int cnt = counts[pair];
    int c0 = blockIdx.y * 64, f0 = blockIdx.x * 64;
    if (c0 >= cnt) return;
    __shared__ float As[64][17];
    __shared__ float Bs[16][65];
    __shared__ int slots[64];
    int tx = threadIdx.x, ty = threadIdx.y;
    int tid = ty * 16 + tx;
    if (tid < 64) slots[tid] = slot_token[pair * kC + c0 + tid];
    __syncthreads();
    float acc[4][4];
    #pragma unroll
    for (int i = 0; i < 4; i++)
        #pragma unroll
        for (int j = 0; j < 4; j++) acc[i][j] = 0.f;
    int ar = tid >> 2, ak = (tid & 3) * 4;
    int bd = tid >> 4, bf = (tid & 15) * 4;
    const float* wie = wi + (size_t)e * kD * kF;
    for (int k0 = 0; k0 < kD; k0 += 16) {
        int sl = slots[ar];
        if (sl >= 0) {
            float4 v = *(const float4*)(hidden + (size_t)(b * kS + sl) * kD + k0 + ak);
            As[ar][ak] = v.x; As[ar][ak + 1] = v.y; As[ar][ak + 2] = v.z; As[ar][ak + 3] = v.w;
        } else {
            As[ar][ak] = 0.f; As[ar][ak + 1] = 0.f; As[ar][ak + 2] = 0.f; As[ar][ak + 3] = 0.f;
        }
        float4 wv = *(const float4*)(wie + (size_t)(k0 + bd) * kF + f0 + bf);
        Bs[bd][bf] = wv.x; Bs[bd][bf + 1] = wv.y; Bs[bd][bf + 2] = wv.z; Bs[bd][bf + 3] = wv.w;
        __syncthreads();
        #pragma unroll
        for (int kk = 0; kk < 16; kk++) {
            float a[4], bv[4];
            #pragma unroll
            for (int i = 0; i < 4; i++) a[i] = As[ty * 4 + i][kk];
            #pragma unroll
            for (int j = 0; j < 4; j++) bv[j] = Bs[kk][tx * 4 + j];
            #pragma unroll
            for (int i = 0; i < 4; i++)
                #pragma unroll
                for (int j = 0; j < 4; j++) acc[i][j] += a[i] * bv[j];
        }
        __syncthreads();
    }
    #pragma unroll
    for (int i = 0; i < 4; i++) {
        int row = c0 + ty * 4 + i;
        #pragma unroll
        for (int j = 0; j < 4; j++)
            H[(size_t)row * kF + f0 + tx * 4 + j] = fmaxf(acc[i][j], 0.f);
    }
}

__global__ __launch_bounds__(256) void ngemm2_k(
    const float* __restrict__ H, const float* __restrict__ wo,
    const int* __restrict__ slot_token, const int* __restrict__ counts,
    const float* __restrict__ maxprob, float* __restrict__ outp, int pair)
{
    int b = pair >> 3, e = pair & 7;
    int cnt = counts[pair];
    int c0 = blockIdx.y * 64, d0 = blockIdx.x * 64;
    if (c0 >= cnt) return;
    __shared__ float As[64][17];
    __shared__ float Bs[16][65];
    __shared__ int slots[64];
    int tx = threadIdx.x, ty = threadIdx.y;
    int tid = ty * 16 + tx;
    if (tid < 64) slots[tid] = slot_token[pair * kC + c0 + tid];
    __syncthreads();
    float acc[4][4];
    #pragma unroll
    for (int i = 0; i < 4; i++)
        #pragma unroll
        for (int j = 0; j < 4; j++) acc[i][j] = 0.f;
    int ar = tid >> 2, ak = (tid & 3) * 4;
    int bd = tid >> 4, bf = (tid & 15) * 4;
    const float* woe = wo + (size_t)e * kF * kD;
    for (int k0 = 0; k0 < kF; k0 += 16) {
        float4 v = *(const float4*)(H + (size_t)(c0 + ar) * kF + k0 + ak);
        As[ar][ak] = v.x; As[ar][ak + 1] = v.y; As[ar][ak + 2] = v.z; As[ar][ak + 3] = v.w;
        float4 wv = *(const float4*)(woe + (size_t)(k0 + bd) * kD + d0 + bf);
        Bs[bd][bf] = wv.x; Bs[bd][bf + 1] = wv.y; Bs[bd][bf + 2] = wv.z; Bs[bd][bf + 3] = wv.w;
        __syncthreads();
        #pragma unroll
        for (int kk = 0; kk < 16; kk++) {
            float a[4], bv[4];
            #pragma unroll
            for (int i = 0; i < 4; i++) a[i] = As[ty * 4 + i][kk];
            #pragma unroll
            for (int j = 0; j < 4; j++) bv[j] = Bs[kk][tx * 4 + j];
            #pragma unroll
            for (int i = 0; i < 4; i++)
                #pragma unroll
                for (int j = 0; j < 4; j++) acc[i][j] += a[i] * bv[j];
        }
        __syncthreads();
    }
    #pragma unroll
    for (int i = 0; i < 4; i++) {
        int s = slots[ty * 4 + i];
        if (s >= 0) {
            float p = maxprob[b * kS + s];
            size_t ob = (size_t)(b * kS + s) * kD;
            #pragma unroll
            for (int j = 0; j < 4; j++)
                outp[ob + d0 + tx * 4 + j] = acc[i][j] * p;
        }
    }
}

extern "C" void kernel_launch(void* const* d_in, const int* in_sizes, int n_in,
                              void* d_out, int out_size, void* d_ws, size_t ws_size,
                              hipStream_t stream)
{
    const float* hidden = (const float*)d_in[0];
    const float* rw     = (const float*)d_in[1];
    const float* wi     = (const float*)d_in[2];
    const float* wo     = (const float*)d_in[3];
    float* outp   = (float*)d_out;
    float* logits = outp + (size_t)kB * kS * kD;
    float* expidx = logits + (size_t)kB * kS * kE;

    char* ws = (char*)d_ws;
    size_t off = 0;
    auto alloc = [&](size_t bytes) -> char* {
        char* p = ws + off; off += (bytes + 255) & ~(size_t)255; return p;
    };
    int*   slot_token = (int*)  alloc((size_t)kB * kE * kC * 4);
    int*   counts     = (int*)  alloc((size_t)kB * kE * 4);
    int*   expert_id  = (int*)  alloc((size_t)kB * kS * 4);
    float* maxprob    = (float*)alloc((size_t)kB * kS * 4);
    size_t small_off = off;

    const size_t wsz   = (size_t)kD * kF * 2;       // 8 MiB per expert, bf16
    const size_t hsz   = (size_t)kC * kF * 2;       // 4 MiB per pair, bf16
    const size_t hbfsz = (size_t)kB * kS * kD * 2;  // 32 MiB bf16 hidden image

    hipFuncSetAttribute(reinterpret_cast<const void*>(gemm1_8p),
                        hipFuncAttributeMaxDynamicSharedMemorySize, kSmemBytes);
    hipFuncSetAttribute(reinterpret_cast<const void*>(gemm2_8p),
                        hipFuncAttributeMaxDynamicSharedMemorySize, kSmemBytes);

    bool tierA = ws_size >= small_off + 2 * kE * wsz + hbfsz + 4096 + 4 * hsz;
    bool tierB = !tierA && ws_size >= small_off + 2 * wsz + hbfsz + 4096 + hsz;

    if (tierA) {
        u16* wiT = (u16*)alloc(kE * wsz);   // 64 MiB
        u16* woT = (u16*)alloc(kE * wsz);   // 64 MiB
        u16* hbf = (u16*)alloc(hbfsz);      // 32 MiB
        u16* zerobuf = (u16*)alloc(4096);
        int Gb = (int)((ws_size - off) / hsz);
        if (Gb > kB * kE) Gb = kB * kE;
        if (Gb < 1) Gb = 1;
        u16* Hbuf = (u16*)alloc((size_t)Gb * hsz);

        init_k<<<2048, 256, 0, stream>>>((uint4*)outp, (uint4*)zerobuf);
        router_k<<<kB * kS / 4, 256, 0, stream>>>(hidden, rw, logits, expert_id, maxprob, hbf);
        scan_k<<<kB, 64, 0, stream>>>(expert_id, slot_token, counts, expidx);
        transpose_v<<<dim3(kF / 64, kD / 64, kE), 256, 0, stream>>>(wi, wiT, kD, kF);
        transpose_v<<<dim3(kD / 64, kF / 64, kE), 256, 0, stream>>>(wo, woT, kF, kD);

        if (Gb == kB * kE) {
            // persistent full-problem dispatches: 256 blocks, B-panel affinity
            gemm1_8p<<<256, 512, kSmemBytes, stream>>>(
                hbf, wiT, (size_t)kD * kF, slot_token, counts, zerobuf, Hbuf, 0, 2048, 1);
            gemm2_8p<<<256, 512, kSmemBytes, stream>>>(
                Hbuf, woT, (size_t)kD * kF, slot_token, counts, maxprob, outp, 0, 512, 1);
        } else {
            for (int p0 = 0; p0 < kB * kE; p0 += Gb) {
                int g = kB * kE - p0 < Gb ? kB * kE - p0 : Gb;
                gemm1_8p<<<g * 2 * (kF / 256), 512, kSmemBytes, stream>>>(
                    hbf, wiT, (size_t)kD * kF, slot_token, counts, zerobuf, Hbuf,
                    p0, g * 2 * (kF / 256), 0);
                gemm2_8p<<<g * 2 * (kD / 256), 512, kSmemBytes, stream>>>(
                    Hbuf, woT, (size_t)kD * kF, slot_token, counts, maxprob, outp,
                    p0, g * 2 * (kD / 256), 0);
            }
        }
    } else if (tierB) {
        u16* wiT = (u16*)alloc(wsz);
        u16* woT = (u16*)alloc(wsz);
        u16* hbf = (u16*)alloc(hbfsz);
        u16* zerobuf = (u16*)alloc(4096);
        int Gb = (int)((ws_size - off) / hsz);
        if (Gb > kB) Gb = kB;
        if (Gb < 1) Gb = 1;
        u16* Hbuf = (u16*)alloc((size_t)Gb * hsz);

        init_k<<<2048, 256, 0, stream>>>((uint4*)outp, (uint4*)zerobuf);
        router_k<<<kB * kS / 4, 256, 0, stream>>>(hidden, rw, logits, expert_id, maxprob, hbf);
        scan_k<<<kB, 64, 0, stream>>>(expert_id, slot_token, counts, expidx);
        for (int e = 0; e < kE; e++) {
            transpose_v<<<dim3(kF / 64, kD / 64, 1), 256, 0, stream>>>(
                wi + (size_t)e * kD * kF, wiT, kD, kF);
            transpose_v<<<dim3(kD / 64, kF / 64, 1), 256, 0, stream>>>(
                wo + (size_t)e * kD * kF, woT, kF, kD);
            for (int b0 = 0; b0 < kB; b0 += Gb) {
                int g = kB - b0 < Gb ? kB - b0 : Gb;
                int p0 = e * 8 + b0;
                gemm1_8p<<<g * 2 * (kF / 256), 512, kSmemBytes, stream>>>(
                    hbf, wiT, 0, slot_token, counts, zerobuf, Hbuf, p0, g * 2 * (kF / 256), 0);
                gemm2_8p<<<g * 2 * (kD / 256), 512, kSmemBytes, stream>>>(
                    Hbuf, woT, 0, slot_token, counts, maxprob, outp, p0, g * 2 * (kD / 256), 0);
            }
        }
    } else {
        float* H = (float*)alloc((size_t)kC * kF * 4);
        init_k<<<2048, 256, 0, stream>>>((uint4*)outp, nullptr);
        router_k<<<kB * kS / 4, 256, 0, stream>>>(hidden, rw, logits, expert_id, maxprob, nullptr);
        scan_k<<<kB, 64, 0, stream>>>(expert_id, slot_token, counts, expidx);
        for (int pair = 0; pair < kB * kE; pair++) {
            ngemm1_k<<<dim3(kF / 64, kC / 64), dim3(16, 16), 0, stream>>>(
                hidden, wi, slot_token, counts, H, pair);
            ngemm2_k<<<dim3(kD / 64, kC / 64), dim3(16, 16), 0, stream>>>(
                H, wo, slot_token, counts, maxprob, outp, pair);
        }
    }
}

// Round 15
// 811.727 us; speedup vs baseline: 1.4345x; 1.0266x over previous
//
#include <hip/hip_runtime.h>
#include <stdint.h>

static constexpr int kB = 8, kS = 2048, kD = 1024, kF = 4096, kE = 8, kC = 512;

typedef unsigned short u16;
typedef __attribute__((ext_vector_type(8))) short bf16x8;
typedef __attribute__((ext_vector_type(4))) float f32x4;

__device__ __forceinline__ u16 f2bf(float f) {
    union { float f; uint32_t u; } v; v.f = f;
    return (u16)((v.u + 0x7fffu + ((v.u >> 16) & 1u)) >> 16);
}
__device__ __forceinline__ void gload16(const u16* g, u16* l) {
    __builtin_amdgcn_global_load_lds(
        (__attribute__((address_space(1))) void*)(u16*)g,
        (__attribute__((address_space(3))) void*)l, 16, 0, 0);
}

static constexpr int kSmemBytes = 132096;  // A 64KB + B 64KB + slots 1KB

// ---------------- init: zero the fp32 `out` region of d_out + zero page ----------------
__global__ void init_k(uint4* __restrict__ outz, uint4* __restrict__ zb) {
    if (blockIdx.x == 0 && zb && threadIdx.x < 256) zb[threadIdx.x] = (uint4){0, 0, 0, 0};
    const size_t n = (size_t)kB * kS * kD * 4 / 16;
    size_t stride = (size_t)gridDim.x * blockDim.x;
    for (size_t i = (size_t)blockIdx.x * blockDim.x + threadIdx.x; i < n; i += stride)
        outz[i] = (uint4){0, 0, 0, 0};
}

// ---------------- router (fused): fp32 logits + argmax + writes bf16 hidden image ----------
__global__ __launch_bounds__(256) void router_k(
    const float* __restrict__ hidden, const float* __restrict__ rw,
    float* __restrict__ logits_out, int* __restrict__ expert_id, float* __restrict__ maxprob,
    u16* __restrict__ hbf)
{
    int token = blockIdx.x * 4 + (threadIdx.x >> 6);
    int lane = threadIdx.x & 63;
    const float* hrow = hidden + (size_t)token * kD;
    float acc[8] = {0, 0, 0, 0, 0, 0, 0, 0};
    for (int d0 = lane * 4; d0 < kD; d0 += 256) {
        float4 h4 = *(const float4*)(hrow + d0);
        float hv[4] = {h4.x, h4.y, h4.z, h4.w};
        if (hbf) {
            u16 t4[4] = {f2bf(h4.x), f2bf(h4.y), f2bf(h4.z), f2bf(h4.w)};
            *(uint2*)(hbf + (size_t)token * kD + d0) = *(const uint2*)t4;
        }
        #pragma unroll
        for (int j = 0; j < 4; j++) {
            const float* wr = rw + (size_t)(d0 + j) * 8;
            float4 w0 = *(const float4*)wr, w1 = *(const float4*)(wr + 4);
            acc[0] += hv[j] * w0.x; acc[1] += hv[j] * w0.y;
            acc[2] += hv[j] * w0.z; acc[3] += hv[j] * w0.w;
            acc[4] += hv[j] * w1.x; acc[5] += hv[j] * w1.y;
            acc[6] += hv[j] * w1.z; acc[7] += hv[j] * w1.w;
        }
    }
    #pragma unroll
    for (int off = 32; off >= 1; off >>= 1) {
        #pragma unroll
        for (int e = 0; e < 8; e++) acc[e] += __shfl_down(acc[e], off, 64);
    }
    if (lane == 0) {
        float m = acc[0];
        #pragma unroll
        for (int e = 1; e < 8; e++) m = fmaxf(m, acc[e]);
        float ex[8], s = 0.f;
        #pragma unroll
        for (int e = 0; e < 8; e++) { ex[e] = expf(acc[e] - m); s += ex[e]; }
        int best = 0; float bv = -1.f;
        #pragma unroll
        for (int e = 0; e < 8; e++) {
            float p = ex[e] / s;
            if (p > bv) { bv = p; best = e; }
            logits_out[(size_t)token * 8 + e] = acc[e];
        }
        expert_id[token] = best;
        maxprob[token] = bv;
    }
}

// ---------------- capacity scan (proven) ----------------
__global__ __launch_bounds__(64) void scan_k(
    const int* __restrict__ expert_id, int* __restrict__ slot_token,
    int* __restrict__ counts, float* __restrict__ expidx_out)
{
    __shared__ int eids[kS];
    int b = blockIdx.x, tid = threadIdx.x;
    for (int s = tid; s < kS; s += 64) eids[s] = expert_id[b * kS + s];
    __syncthreads();
    if (tid < kE) {
        int e = tid, cnt = 0;
        for (int s = 0; s < kS; s++) {
            if (eids[s] == e) {
                if (cnt < kC) {
                    slot_token[(b * kE + e) * kC + cnt] = s;
                    expidx_out[b * kS + s] = (float)e;
                    cnt++;
                } else {
                    expidx_out[b * kS + s] = 0.f;
                }
            }
        }
        counts[b * kE + e] = cnt;
        for (int c = cnt; c < kC; c++) slot_token[(b * kE + e) * kC + c] = -1;
    }
}

// ---------------- build compacted tile list: glist[i] = (pem<<1)|mt, expert-major ----------
__global__ void build_k(const int* __restrict__ counts, int* __restrict__ glist,
                        int* __restrict__ ngp) {
    if (threadIdx.x == 0 && blockIdx.x == 0) {
        int n = 0;
        for (int e = 0; e < kE; e++)
            for (int b = 0; b < kB; b++) {
                int cnt = counts[b * kE + e];
                int pem = e * 8 + b;
                if (cnt > 0)   glist[n++] = (pem << 1);
                if (cnt > 256) glist[n++] = (pem << 1) | 1;
            }
        *ngp = n;
    }
}

// ---------------- vectorized convert-transpose: fp32 [R][Cn] -> bf16 [Cn][R] ----------------
__global__ __launch_bounds__(256) void transpose_v(
    const float* __restrict__ src, u16* __restrict__ dst, int R, int Cn)
{
    __shared__ u16 tl[64][68];
    size_t eo = (size_t)blockIdx.z * R * Cn;
    int c0 = blockIdx.x * 64, r0 = blockIdx.y * 64;
    int t = threadIdx.x;
    int tx = t & 15, ty = t >> 4;
    #pragma unroll
    for (int i = 0; i < 4; i++) {
        int r = ty + 16 * i;
        float4 v = *(const float4*)(src + eo + (size_t)(r0 + r) * Cn + c0 + tx * 4);
        tl[tx * 4 + 0][r] = f2bf(v.x);
        tl[tx * 4 + 1][r] = f2bf(v.y);
        tl[tx * 4 + 2][r] = f2bf(v.z);
        tl[tx * 4 + 3][r] = f2bf(v.w);
    }
    __syncthreads();
    int seg = t & 7, clb = t >> 3;
    #pragma unroll
    for (int ii = 0; ii < 2; ii++) {
        int cl = clb + 32 * ii;
        uint4 v = *(const uint4*)&tl[cl][seg * 8];
        *(uint4*)(dst + eo + (size_t)(c0 + cl) * R + r0 + seg * 8) = v;
    }
}

// ================= 8-phase 256x256 MFMA GEMM, persistent + compacted queue =================
#define SA8(kt, kh) { int off_ = (((kt) & 1) << 14) + ((kh) << 13); int go_ = (kt) * 64 + (kh) * 32; \
    gload16(sA0 + go_, dA + off_); gload16(sA1 + go_, dA + off_ + 512); }
#define SB8(kt, kh) { int off_ = (((kt) & 1) << 14) + ((kh) << 13); int go_ = (kt) * 64 + (kh) * 32; \
    gload16(sB0 + go_, dB + off_); gload16(sB1 + go_, dB + off_ + 512); }
#define RD8(buf, kh) { const u16* a_ = rA + ((buf) << 14) + ((kh) << 13); \
    const u16* b_ = rB + ((buf) << 14) + ((kh) << 13); \
    _Pragma("unroll") for (int m_ = 0; m_ < 8; m_++) af[m_] = *(const bf16x8*)(a_ + m_ * 512); \
    _Pragma("unroll") for (int n_ = 0; n_ < 4; n_++) bfr[n_] = *(const bf16x8*)(b_ + n_ * 512); }
#define MM8(mlo) { _Pragma("unroll") for (int m_ = 0; m_ < 4; m_++) \
    { _Pragma("unroll") for (int n_ = 0; n_ < 4; n_++) \
      acc[(mlo) + m_][n_] = __builtin_amdgcn_mfma_f32_16x16x32_bf16(af[(mlo) + m_], bfr[n_], acc[(mlo) + m_][n_], 0, 0, 0); } }
#define PH_MID() __builtin_amdgcn_sched_barrier(0); __builtin_amdgcn_s_barrier(); \
    asm volatile("s_waitcnt lgkmcnt(0)" ::: "memory"); __builtin_amdgcn_sched_barrier(0); \
    __builtin_amdgcn_s_setprio(1)
#define PH_END() __builtin_amdgcn_s_setprio(0); __builtin_amdgcn_sched_barrier(0); \
    __builtin_amdgcn_s_barrier(); __builtin_amdgcn_sched_barrier(0)
#define PH_END_VM(n) __builtin_amdgcn_s_setprio(0); __builtin_amdgcn_sched_barrier(0); \
    asm volatile("s_waitcnt vmcnt(" #n ")" ::: "memory"); \
    __builtin_amdgcn_s_barrier(); __builtin_amdgcn_sched_barrier(0)

// ---------------- GEMM1 (8-phase, persistent): H = relu(gather(hbf) @ wiT^T) ----------------
__global__ __launch_bounds__(512, 1) void gemm1_8p(
    const u16* __restrict__ hbf, const u16* __restrict__ wiT, size_t wstride,
    const int* __restrict__ slot_token, const int* __restrict__ counts,
    const u16* __restrict__ zerobuf, u16* __restrict__ Hbuf,
    int p0, int nItems, const int* __restrict__ glist, const int* __restrict__ ngp)
{
    constexpr int KDIM = kD, NTn = kF / 256, NKT = KDIM / 64, NI = NKT / 2;
    int tid = threadIdx.x, w = tid >> 6, l = tid & 63;
    int wr = w >> 2, wc = w & 3;
    int fr = l & 15, fq = l >> 4;
    int r0 = w * 32 + (l >> 2), r1 = r0 + 16;
    int clog = (l & 3) ^ ((l >> 3) & 3);
    int sw = (fr >> 1) & 3;

    extern __shared__ __align__(16) u16 lds[];
    u16* Ap = lds;
    u16* Bp = lds + 32768;
    int* slots = (int*)(lds + 65536);
    u16* dA = Ap + w * 1024;
    u16* dB = Bp + w * 1024;
    const u16* rA = Ap + (wr * 128 + fr) * 32 + ((fq ^ sw) << 3);
    const u16* rB = Bp + (wc * 64 + fr) * 32 + ((fq ^ sw) << 3);
    int nblk = gridDim.x;
    int nI = glist ? (*ngp) * NTn : nItems;

    #pragma unroll 1
    for (int i = blockIdx.x; i < nI; i += nblk) {
        int pem, mt, nt, pl;
        if (glist) {
            int gpk = glist[i / NTn];
            nt = i % NTn;
            pem = gpk >> 1; mt = gpk & 1; pl = pem;
        } else {
            nt = i % NTn;
            int g = i / NTn;
            mt = g & 1; pem = p0 + (g >> 1); pl = pem - p0;
        }
        int e = pem >> 3, b = pem & 7;
        int pair = b * kE + e;
        if (!glist) {
            int cnt = counts[pair];
            if (mt * 256 >= cnt) continue;
        }

        if (tid < 256) slots[tid] = slot_token[pair * kC + mt * 256 + tid];
        __syncthreads();

        int sl0 = slots[r0], sl1 = slots[r1];
        const u16* sA0 = (sl0 >= 0) ? hbf + (size_t)(b * kS + sl0) * kD + clog * 8 : zerobuf + clog * 8;
        const u16* sA1 = (sl1 >= 0) ? hbf + (size_t)(b * kS + sl1) * kD + clog * 8 : zerobuf + clog * 8;
        const u16* wbase = wiT + (size_t)e * wstride;
        const u16* sB0 = wbase + (size_t)(nt * 256 + r0) * KDIM + clog * 8;
        const u16* sB1 = wbase + (size_t)(nt * 256 + r1) * KDIM + clog * 8;

        f32x4 acc[8][4];
        #pragma unroll
        for (int m = 0; m < 8; m++)
            #pragma unroll
            for (int n = 0; n < 4; n++) acc[m][n] = (f32x4){0.f, 0.f, 0.f, 0.f};
        bf16x8 af[8], bfr[4];

        SA8(0, 0) SB8(0, 0) SA8(0, 1) SB8(0, 1) SA8(1, 0) SB8(1, 0) SA8(1, 1)
        asm volatile("s_waitcnt vmcnt(6)" ::: "memory");
        __builtin_amdgcn_s_barrier();
        __builtin_amdgcn_sched_barrier(0);

        #pragma unroll 1
        for (int i2 = 0; i2 < NI - 1; ++i2) {
            int kt0 = 2 * i2;
            RD8(0, 0) SB8(kt0 + 1, 1) PH_MID(); MM8(0) PH_END();
            SA8(kt0 + 2, 0)           PH_MID(); MM8(4) PH_END();
            RD8(0, 1) SB8(kt0 + 2, 0) PH_MID(); MM8(0) PH_END();
            SA8(kt0 + 2, 1)           PH_MID(); MM8(4) PH_END_VM(6);
            RD8(1, 0) SB8(kt0 + 2, 1) PH_MID(); MM8(0) PH_END();
            SA8(kt0 + 3, 0)           PH_MID(); MM8(4) PH_END();
            RD8(1, 1) SB8(kt0 + 3, 0) PH_MID(); MM8(0) PH_END();
            SA8(kt0 + 3, 1)           PH_MID(); MM8(4) PH_END_VM(6);
        }
        RD8(0, 0) SB8(NKT - 1, 1) PH_MID(); MM8(0) PH_END();
        PH_MID(); MM8(4) PH_END();
        RD8(0, 1) PH_MID(); MM8(0) PH_END();
        PH_MID(); MM8(4) PH_END_VM(0);
        RD8(1, 0) PH_MID(); MM8(0) PH_END();
        PH_MID(); MM8(4) PH_END();
        RD8(1, 1) PH_MID(); MM8(0) PH_END();
        PH_MID(); MM8(4) __builtin_amdgcn_s_setprio(0); __builtin_amdgcn_sched_barrier(0);

        size_t hbase = (size_t)pl * kC * kF;
        int rbase = mt * 256 + wr * 128, c0 = nt * 256 + wc * 64;
        #pragma unroll
        for (int m = 0; m < 8; m++) {
            #pragma unroll
            for (int j = 0; j < 4; j++) {
                int row = rbase + m * 16 + fq * 4 + j;
                size_t rb = hbase + (size_t)row * kF;
                #pragma unroll
                for (int n = 0; n < 4; n++)
                    Hbuf[rb + c0 + n * 16 + fr] = f2bf(fmaxf(acc[m][n][j], 0.f));
            }
        }
        __syncthreads();   // protect slots[] before next item
    }
}

// ---------------- GEMM2 (8-phase, persistent): out = (H @ woT^T) * max_prob ----------------
__global__ __launch_bounds__(512, 1) void gemm2_8p(
    const u16* __restrict__ Hbuf, const u16* __restrict__ woT, size_t wstride,
    const int* __restrict__ slot_token, const int* __restrict__ counts,
    const float* __restrict__ maxprob, float* __restrict__ outp,
    int p0, int nItems, const int* __restrict__ glist, const int* __restrict__ ngp)
{
    constexpr int KDIM = kF, NTn = kD / 256, NKT = KDIM / 64, NI = NKT / 2;
    int tid = threadIdx.x, w = tid >> 6, l = tid & 63;
    int wr = w >> 2, wc = w & 3;
    int fr = l & 15, fq = l >> 4;
    int r0 = w * 32 + (l >> 2), r1 = r0 + 16;
    int clog = (l & 3) ^ ((l >> 3) & 3);
    int sw = (fr >> 1) & 3;

    extern __shared__ __align__(16) u16 lds[];
    u16* Ap = lds;
    u16* Bp = lds + 32768;
    int* slots = (int*)(lds + 65536);
    u16* dA = Ap + w * 1024;
    u16* dB = Bp + w * 1024;
    const u16* rA = Ap + (wr * 128 + fr) * 32 + ((fq ^ sw) << 3);
    const u16* rB = Bp + (wc * 64 + fr) * 32 + ((fq ^ sw) << 3);
    int nblk = gridDim.x;
    int nI = glist ? (*ngp) * NTn : nItems;

    #pragma unroll 1
    for (int i = blockIdx.x; i < nI; i += nblk) {
        int pem, mt, nt, pl;
        if (glist) {
            int gpk = glist[i / NTn];
            nt = i % NTn;
            pem = gpk >> 1; mt = gpk & 1; pl = pem;
        } else {
            nt = i % NTn;
            int g = i / NTn;
            mt = g & 1; pem = p0 + (g >> 1); pl = pem - p0;
        }
        int e = pem >> 3, b = pem & 7;
        int pair = b * kE + e;
        if (!glist) {
            int cnt = counts[pair];
            if (mt * 256 >= cnt) continue;
        }

        if (tid < 256) slots[tid] = slot_token[pair * kC + mt * 256 + tid];
        __syncthreads();

        const u16* sA0 = Hbuf + ((size_t)pl * kC + mt * 256 + r0) * kF + clog * 8;
        const u16* sA1 = Hbuf + ((size_t)pl * kC + mt * 256 + r1) * kF + clog * 8;
        const u16* wbase = woT + (size_t)e * wstride;
        const u16* sB0 = wbase + (size_t)(nt * 256 + r0) * KDIM + clog * 8;
        const u16* sB1 = wbase + (size_t)(nt * 256 + r1) * KDIM + clog * 8;

        f32x4 acc[8][4];
        #pragma unroll
        for (int m = 0; m < 8; m++)
            #pragma unroll
            for (int n = 0; n < 4; n++) acc[m][n] = (f32x4){0.f, 0.f, 0.f, 0.f};
        bf16x8 af[8], bfr[4];

        SA8(0, 0) SB8(0, 0) SA8(0, 1) SB8(0, 1) SA8(1, 0) SB8(1, 0) SA8(1, 1)
        asm volatile("s_waitcnt vmcnt(6)" ::: "memory");
        __builtin_amdgcn_s_barrier();
        __builtin_amdgcn_sched_barrier(0);

        #pragma unroll 1
        for (int i2 = 0; i2 < NI - 1; ++i2) {
            int kt0 = 2 * i2;
            RD8(0, 0) SB8(kt0 + 1, 1) PH_MID(); MM8(0) PH_END();
            SA8(kt0 + 2, 0)           PH_MID(); MM8(4) PH_END();
            RD8(0, 1) SB8(kt0 + 2, 0) PH_MID(); MM8(0) PH_END();
            SA8(kt0 + 2, 1)           PH_MID(); MM8(4) PH_END_VM(6);
            RD8(1, 0) SB8(kt0 + 2, 1) PH_MID(); MM8(0) PH_END();
            SA8(kt0 + 3, 0)           PH_MID(); MM8(4) PH_END();
            RD8(1, 1) SB8(kt0 + 3, 0) PH_MID(); MM8(0) PH_END();
            SA8(kt0 + 3, 1)           PH_MID(); MM8(4) PH_END_VM(6);
        }
        RD8(0, 0) SB8(NKT - 1, 1) PH_MID(); MM8(0) PH_END();
        PH_MID(); MM8(4) PH_END();
        RD8(0, 1) PH_MID(); MM8(0) PH_END();
        PH_MID(); MM8(4) PH_END_VM(0);
        RD8(1, 0) PH_MID(); MM8(0) PH_END();
        PH_MID(); MM8(4) PH_END();
        RD8(1, 1) PH_MID(); MM8(0) PH_END();
        PH_MID(); MM8(4) __builtin_amdgcn_s_setprio(0); __builtin_amdgcn_sched_barrier(0);

        int c0 = nt * 256 + wc * 64;
        #pragma unroll
        for (int m = 0; m < 8; m++) {
            #pragma unroll
            for (int j = 0; j < 4; j++) {
                int rl = wr * 128 + m * 16 + fq * 4 + j;
                int s = slots[rl];
                if (s >= 0) {
                    float p = maxprob[b * kS + s];
                    size_t ob = (size_t)(b * kS + s) * kD;
                    #pragma unroll
                    for (int n = 0; n < 4; n++)
                        outp[ob + c0 + n * 16 + fr] = acc[m][n][j] * p;
                }
            }
        }
        __syncthreads();   // protect slots[] before next item
    }
}

#undef SA8
#undef SB8
#undef RD8
#undef MM8
#undef PH_MID
#undef PH_END
#undef PH_END_VM

// ---------------- naive fp32 fallback (proven) ----------------
__global__ __launch_bounds__(256) void ngemm1_k(
    const float* __restrict__ hidden, const float* __restrict__ wi,
    const int* __restrict__ slot_token, const int* __restrict__ counts,
    float* __restrict__ H, int pair)
{
    int b = pair >> 3, e = pair & 7;
    int cnt = counts[pair];
    int c0 = blockIdx.y * 64, f0 = blockIdx.x * 64;
    if (c0 >= cnt) return;
    __shared__ float As[64][17];
    __shared__ float Bs[16][65];
    __shared__ int slots[64];
    int tx = threadIdx.x, ty = threadIdx.y;
    int tid = ty * 16 + tx;
    if (tid < 64) slots[tid] = slot_token[pair * kC + c0 + tid];
    __syncthreads();
    float acc[4][4];
    #pragma unroll
    for (int i = 0; i < 4; i++)
        #pragma unroll
        for (int j = 0; j < 4; j++) acc[i][j] = 0.f;
    int ar = tid >> 2, ak = (tid & 3) * 4;
    int bd = tid >> 4, bf = (tid & 15) * 4;
    const float* wie = wi + (size_t)e * kD * kF;
    for (int k0 = 0; k0 < kD; k0 += 16) {
        int sl = slots[ar];
        if (sl >= 0) {
            float4 v = *(const float4*)(hidden + (size_t)(b * kS + sl) * kD + k0 + ak);
            As[ar][ak] = v.x; As[ar][ak + 1] = v.y; As[ar][ak + 2] = v.z; As[ar][ak + 3] = v.w;
        } else {
            As[ar][ak] = 0.f; As[ar][ak + 1] = 0.f; As[ar][ak + 2] = 0.f; As[ar][ak + 3] = 0.f;
        }
        float4 wv = *(const float4*)(wie + (size_t)(k0 + bd) * kF + f0 + bf);
        Bs[bd][bf] = wv.x; Bs[bd][bf + 1] = wv.y; Bs[bd][bf + 2] = wv.z; Bs[bd][bf + 3] = wv.w;
        __syncthreads();
        #pragma unroll
        for (int kk = 0; kk < 16; kk++) {
            float a[4], bv[4];
            #pragma unroll
            for (int i = 0; i < 4; i++) a[i] = As[ty * 4 + i][kk];
            #pragma unroll
            for (int j = 0; j < 4; j++) bv[j] = Bs[kk][tx * 4 + j];
            #pragma unroll
            for (int i = 0; i < 4; i++)
                #pragma unroll
                for (int j = 0; j < 4; j++) acc[i][j] += a[i] * bv[j];
        }
        __syncthreads();
    }
    #pragma unroll
    for (int i = 0; i < 4; i++) {
        int row = c0 + ty * 4 + i;
        #pragma unroll
        for (int j = 0; j < 4; j++)
            H[(size_t)row * kF + f0 + tx * 4 + j] = fmaxf(acc[i][j], 0.f);
    }
}

__global__ __launch_bounds__(256) void ngemm2_k(
    const float* __restrict__ H, const float* __restrict__ wo,
    const int* __restrict__ slot_token, const int* __restrict__ counts,
    const float* __restrict__ maxprob, float* __restrict__ outp, int pair)
{
    int b = pair >> 3, e = pair & 7;
    int cnt = counts[pair];
    int c0 = blockIdx.y * 64, d0 = blockIdx.x * 64;
    if (c0 >= cnt) return;
    __shared__ float As[64][17];
    __shared__ float Bs[16][65];
    __shared__ int slots[64];
    int tx = threadIdx.x, ty = threadIdx.y;
    int tid = ty * 16 + tx;
    if (tid < 64) slots[tid] = slot_token[pair * kC + c0 + tid];
    __syncthreads();
    float acc[4][4];
    #pragma unroll
    for (int i = 0; i < 4; i++)
        #pragma unroll
        for (int j = 0; j < 4; j++) acc[i][j] = 0.f;
    int ar = tid >> 2, ak = (tid & 3) * 4;
    int bd = tid >> 4, bf = (tid & 15) * 4;
    const float* woe = wo + (size_t)e * kF * kD;
    for (int k0 = 0; k0 < kF; k0 += 16) {
        float4 v = *(const float4*)(H + (size_t)(c0 + ar) * kF + k0 + ak);
        As[ar][ak] = v.x; As[ar][ak + 1] = v.y; As[ar][ak + 2] = v.z; As[ar][ak + 3] = v.w;
        float4 wv = *(const float4*)(woe + (size_t)(k0 + bd) * kD + d0 + bf);
        Bs[bd][bf] = wv.x; Bs[bd][bf + 1] = wv.y; Bs[bd][bf + 2] = wv.z; Bs[bd][bf + 3] = wv.w;
        __syncthreads();
        #pragma unroll
        for (int kk = 0; kk < 16; kk++) {
            float a[4], bv[4];
            #pragma unroll
            for (int i = 0; i < 4; i++) a[i] = As[ty * 4 + i][kk];
            #pragma unroll
            for (int j = 0; j < 4; j++) bv[j] = Bs[kk][tx * 4 + j];
            #pragma unroll
            for (int i = 0; i < 4; i++)
                #pragma unroll
                for (int j = 0; j < 4; j++) acc[i][j] += a[i] * bv[j];
        }
        __syncthreads();
    }
    #pragma unroll
    for (int i = 0; i < 4; i++) {
        int s = slots[ty * 4 + i];
        if (s >= 0) {
            float p = maxprob[b * kS + s];
            size_t ob = (size_t)(b * kS + s) * kD;
            #pragma unroll
            for (int j = 0; j < 4; j++)
                outp[ob + d0 + tx * 4 + j] = acc[i][j] * p;
        }
    }
}

extern "C" void kernel_launch(void* const* d_in, const int* in_sizes, int n_in,
                              void* d_out, int out_size, void* d_ws, size_t ws_size,
                              hipStream_t stream)
{
    const float* hidden = (const float*)d_in[0];
    const float* rw     = (const float*)d_in[1];
    const float* wi     = (const float*)d_in[2];
    const float* wo     = (const float*)d_in[3];
    float* outp   = (float*)d_out;
    float* logits = outp + (size_t)kB * kS * kD;
    float* expidx = logits + (size_t)kB * kS * kE;

    char* ws = (char*)d_ws;
    size_t off = 0;
    auto alloc = [&](size_t bytes) -> char* {
        char* p = ws + off; off += (bytes + 255) & ~(size_t)255; return p;
    };
    int*   slot_token = (int*)  alloc((size_t)kB * kE * kC * 4);
    int*   counts     = (int*)  alloc((size_t)kB * kE * 4);
    int*   expert_id  = (int*)  alloc((size_t)kB * kS * 4);
    float* maxprob    = (float*)alloc((size_t)kB * kS * 4);
    int*   glist      = (int*)  alloc(256 * 4);
    int*   ngp        = (int*)  alloc(256);
    size_t small_off = off;

    const size_t wsz   = (size_t)kD * kF * 2;       // 8 MiB per expert, bf16
    const size_t hsz   = (size_t)kC * kF * 2;       // 4 MiB per pair, bf16
    const size_t hbfsz = (size_t)kB * kS * kD * 2;  // 32 MiB bf16 hidden image

    hipFuncSetAttribute(reinterpret_cast<const void*>(gemm1_8p),
                        hipFuncAttributeMaxDynamicSharedMemorySize, kSmemBytes);
    hipFuncSetAttribute(reinterpret_cast<const void*>(gemm2_8p),
                        hipFuncAttributeMaxDynamicSharedMemorySize, kSmemBytes);

    bool tierA = ws_size >= small_off + 2 * kE * wsz + hbfsz + 4096 + 4 * hsz;
    bool tierB = !tierA && ws_size >= small_off + 2 * wsz + hbfsz + 4096 + hsz;

    if (tierA) {
        u16* wiT = (u16*)alloc(kE * wsz);   // 64 MiB
        u16* woT = (u16*)alloc(kE * wsz);   // 64 MiB
        u16* hbf = (u16*)alloc(hbfsz);      // 32 MiB
        u16* zerobuf = (u16*)alloc(4096);
        int Gb = (int)((ws_size - off) / hsz);
        if (Gb > kB * kE) Gb = kB * kE;
        if (Gb < 1) Gb = 1;
        u16* Hbuf = (u16*)alloc((size_t)Gb * hsz);

        init_k<<<2048, 256, 0, stream>>>((uint4*)outp, (uint4*)zerobuf);
        router_k<<<kB * kS / 4, 256, 0, stream>>>(hidden, rw, logits, expert_id, maxprob, hbf);
        scan_k<<<kB, 64, 0, stream>>>(expert_id, slot_token, counts, expidx);
        build_k<<<1, 64, 0, stream>>>(counts, glist, ngp);
        transpose_v<<<dim3(kF / 64, kD / 64, kE), 256, 0, stream>>>(wi, wiT, kD, kF);
        transpose_v<<<dim3(kD / 64, kF / 64, kE), 256, 0, stream>>>(wo, woT, kF, kD);

        if (Gb == kB * kE) {
            gemm1_8p<<<256, 512, kSmemBytes, stream>>>(
                hbf, wiT, (size_t)kD * kF, slot_token, counts, zerobuf, Hbuf, 0, 0, glist, ngp);
            gemm2_8p<<<256, 512, kSmemBytes, stream>>>(
                Hbuf, woT, (size_t)kD * kF, slot_token, counts, maxprob, outp, 0, 0, glist, ngp);
        } else {
            for (int p0 = 0; p0 < kB * kE; p0 += Gb) {
                int g = kB * kE - p0 < Gb ? kB * kE - p0 : Gb;
                gemm1_8p<<<g * 2 * (kF / 256), 512, kSmemBytes, stream>>>(
                    hbf, wiT, (size_t)kD * kF, slot_token, counts, zerobuf, Hbuf,
                    p0, g * 2 * (kF / 256), nullptr, nullptr);
                gemm2_8p<<<g * 2 * (kD / 256), 512, kSmemBytes, stream>>>(
                    Hbuf, woT, (size_t)kD * kF, slot_token, counts, maxprob, outp,
                    p0, g * 2 * (kD / 256), nullptr, nullptr);
            }
        }
    } else if (tierB) {
        u16* wiT = (u16*)alloc(wsz);
        u16* woT = (u16*)alloc(wsz);
        u16* hbf = (u16*)alloc(hbfsz);
        u16* zerobuf = (u16*)alloc(4096);
        int Gb = (int)((ws_size - off) / hsz);
        if (Gb > kB) Gb = kB;
        if (Gb < 1) Gb = 1;
        u16* Hbuf = (u16*)alloc((size_t)Gb * hsz);

        init_k<<<2048, 256, 0, stream>>>((uint4*)outp, (uint4*)zerobuf);
        router_k<<<kB * kS / 4, 256, 0, stream>>>(hidden, rw, logits, expert_id, maxprob, hbf);
        scan_k<<<kB, 64, 0, stream>>>(expert_id, slot_token, counts, expidx);
        for (int e = 0; e < kE; e++) {
            transpose_v<<<dim3(kF / 64, kD / 64, 1), 256, 0, stream>>>(
                wi + (size_t)e * kD * kF, wiT, kD, kF);
            transpose_v<<<dim3(kD / 64, kF / 64, 1), 256, 0, stream>>>(
                wo + (size_t)e * kD * kF, woT, kF, kD);
            for (int b0 = 0; b0 < kB; b0 += Gb) {
                int g = kB - b0 < Gb ? kB - b0 : Gb;
                int p0 = e * 8 + b0;
                gemm1_8p<<<g * 2 * (kF / 256), 512, kSmemBytes, stream>>>(
                    hbf, wiT, 0, slot_token, counts, zerobuf, Hbuf,
                    p0, g * 2 * (kF / 256), nullptr, nullptr);
                gemm2_8p<<<g * 2 * (kD / 256), 512, kSmemBytes, stream>>>(
                    Hbuf, woT, 0, slot_token, counts, maxprob, outp,
                    p0, g * 2 * (kD / 256), nullptr, nullptr);
            }
        }
    } else {
        float* H = (float*)alloc((size_t)kC * kF * 4);
        init_k<<<2048, 256, 0, stream>>>((uint4*)outp, nullptr);
        router_k<<<kB * kS / 4, 256, 0, stream>>>(hidden, rw, logits, expert_id, maxprob, nullptr);
        scan_k<<<kB, 64, 0, stream>>>(expert_id, slot_token, counts, expidx);
        for (int pair = 0; pair < kB * kE; pair++) {
            ngemm1_k<<<dim3(kF / 64, kC / 64), dim3(16, 16), 0, stream>>>(
                hidden, wi, slot_token, counts, H, pair);
            ngemm2_k<<<dim3(kD / 64, kC / 64), dim3(16, 16), 0, stream>>>(
                H, wo, slot_token, counts, maxprob, outp, pair);
        }
    }
}

// Round 16
// 806.933 us; speedup vs baseline: 1.4430x; 1.0059x over previous
//
#include <hip/hip_runtime.h>
#include <stdint.h>

static constexpr int kB = 8, kS = 2048, kD = 1024, kF = 4096, kE = 8, kC = 512;

typedef unsigned short u16;
typedef __attribute__((ext_vector_type(8))) short bf16x8;
typedef __attribute__((ext_vector_type(4))) float f32x4;

__device__ __forceinline__ u16 f2bf(float f) {
    union { float f; uint32_t u; } v; v.f = f;
    return (u16)((v.u + 0x7fffu + ((v.u >> 16) & 1u)) >> 16);
}
__device__ __forceinline__ void gload16(const u16* g, u16* l) {
    __builtin_amdgcn_global_load_lds(
        (__attribute__((address_space(1))) void*)(u16*)g,
        (__attribute__((address_space(3))) void*)l, 16, 0, 0);
}

static constexpr int kSmemBytes = 132096;  // A 64KB + B 64KB + slots 1KB

// ---------------- init: zero the fp32 `out` region of d_out + zero page ----------------
__global__ void init_k(uint4* __restrict__ outz, uint4* __restrict__ zb) {
    if (blockIdx.x == 0 && zb && threadIdx.x < 256) zb[threadIdx.x] = (uint4){0, 0, 0, 0};
    const size_t n = (size_t)kB * kS * kD * 4 / 16;
    size_t stride = (size_t)gridDim.x * blockDim.x;
    for (size_t i = (size_t)blockIdx.x * blockDim.x + threadIdx.x; i < n; i += stride)
        outz[i] = (uint4){0, 0, 0, 0};
}

// ---------------- router (fused): fp32 logits + argmax + writes bf16 hidden image ----------
__global__ __launch_bounds__(256) void router_k(
    const float* __restrict__ hidden, const float* __restrict__ rw,
    float* __restrict__ logits_out, int* __restrict__ expert_id, float* __restrict__ maxprob,
    u16* __restrict__ hbf)
{
    int token = blockIdx.x * 4 + (threadIdx.x >> 6);
    int lane = threadIdx.x & 63;
    const float* hrow = hidden + (size_t)token * kD;
    float acc[8] = {0, 0, 0, 0, 0, 0, 0, 0};
    for (int d0 = lane * 4; d0 < kD; d0 += 256) {
        float4 h4 = *(const float4*)(hrow + d0);
        float hv[4] = {h4.x, h4.y, h4.z, h4.w};
        if (hbf) {
            u16 t4[4] = {f2bf(h4.x), f2bf(h4.y), f2bf(h4.z), f2bf(h4.w)};
            *(uint2*)(hbf + (size_t)token * kD + d0) = *(const uint2*)t4;
        }
        #pragma unroll
        for (int j = 0; j < 4; j++) {
            const float* wr = rw + (size_t)(d0 + j) * 8;
            float4 w0 = *(const float4*)wr, w1 = *(const float4*)(wr + 4);
            acc[0] += hv[j] * w0.x; acc[1] += hv[j] * w0.y;
            acc[2] += hv[j] * w0.z; acc[3] += hv[j] * w0.w;
            acc[4] += hv[j] * w1.x; acc[5] += hv[j] * w1.y;
            acc[6] += hv[j] * w1.z; acc[7] += hv[j] * w1.w;
        }
    }
    #pragma unroll
    for (int off = 32; off >= 1; off >>= 1) {
        #pragma unroll
        for (int e = 0; e < 8; e++) acc[e] += __shfl_down(acc[e], off, 64);
    }
    if (lane == 0) {
        float m = acc[0];
        #pragma unroll
        for (int e = 1; e < 8; e++) m = fmaxf(m, acc[e]);
        float ex[8], s = 0.f;
        #pragma unroll
        for (int e = 0; e < 8; e++) { ex[e] = expf(acc[e] - m); s += ex[e]; }
        int best = 0; float bv = -1.f;
        #pragma unroll
        for (int e = 0; e < 8; e++) {
            float p = ex[e] / s;
            if (p > bv) { bv = p; best = e; }
            logits_out[(size_t)token * 8 + e] = acc[e];
        }
        expert_id[token] = best;
        maxprob[token] = bv;
    }
}

// ---------------- capacity scan (proven) ----------------
__global__ __launch_bounds__(64) void scan_k(
    const int* __restrict__ expert_id, int* __restrict__ slot_token,
    int* __restrict__ counts, float* __restrict__ expidx_out)
{
    __shared__ int eids[kS];
    int b = blockIdx.x, tid = threadIdx.x;
    for (int s = tid; s < kS; s += 64) eids[s] = expert_id[b * kS + s];
    __syncthreads();
    if (tid < kE) {
        int e = tid, cnt = 0;
        for (int s = 0; s < kS; s++) {
            if (eids[s] == e) {
                if (cnt < kC) {
                    slot_token[(b * kE + e) * kC + cnt] = s;
                    expidx_out[b * kS + s] = (float)e;
                    cnt++;
                } else {
                    expidx_out[b * kS + s] = 0.f;
                }
            }
        }
        counts[b * kE + e] = cnt;
        for (int c = cnt; c < kC; c++) slot_token[(b * kE + e) * kC + c] = -1;
    }
}

// ---------------- build compacted tile list: glist[i] = (pem<<1)|mt, expert-major ----------
__global__ void build_k(const int* __restrict__ counts, int* __restrict__ glist,
                        int* __restrict__ ngp) {
    if (threadIdx.x == 0 && blockIdx.x == 0) {
        int n = 0;
        for (int e = 0; e < kE; e++)
            for (int b = 0; b < kB; b++) {
                int cnt = counts[b * kE + e];
                int pem = e * 8 + b;
                if (cnt > 0)   glist[n++] = (pem << 1);
                if (cnt > 256) glist[n++] = (pem << 1) | 1;
            }
        *ngp = n;
    }
}

// ---------------- vectorized convert-transpose: fp32 [R][Cn] -> bf16 [Cn][R] ----------------
__global__ __launch_bounds__(256) void transpose_v(
    const float* __restrict__ src, u16* __restrict__ dst, int R, int Cn)
{
    __shared__ u16 tl[64][68];
    size_t eo = (size_t)blockIdx.z * R * Cn;
    int c0 = blockIdx.x * 64, r0 = blockIdx.y * 64;
    int t = threadIdx.x;
    int tx = t & 15, ty = t >> 4;
    #pragma unroll
    for (int i = 0; i < 4; i++) {
        int r = ty + 16 * i;
        float4 v = *(const float4*)(src + eo + (size_t)(r0 + r) * Cn + c0 + tx * 4);
        tl[tx * 4 + 0][r] = f2bf(v.x);
        tl[tx * 4 + 1][r] = f2bf(v.y);
        tl[tx * 4 + 2][r] = f2bf(v.z);
        tl[tx * 4 + 3][r] = f2bf(v.w);
    }
    __syncthreads();
    int seg = t & 7, clb = t >> 3;
    #pragma unroll
    for (int ii = 0; ii < 2; ii++) {
        int cl = clb + 32 * ii;
        uint4 v = *(const uint4*)&tl[cl][seg * 8];
        *(uint4*)(dst + eo + (size_t)(c0 + cl) * R + r0 + seg * 8) = v;
    }
}

// ================= 8-phase 256x256 MFMA GEMM, persistent + compacted queue =================
// LDS reads split 8/4 across phase pairs (m201's "4 or 8 x ds_read_b128 per phase"):
// MM8(0)-phase reads af[0..3]+bfr[0..3]; MM8(4)-phase reads af[4..7]; bfr persists.
#define SA8(kt, kh) { int off_ = (((kt) & 1) << 14) + ((kh) << 13); int go_ = (kt) * 64 + (kh) * 32; \
    gload16(sA0 + go_, dA + off_); gload16(sA1 + go_, dA + off_ + 512); }
#define SB8(kt, kh) { int off_ = (((kt) & 1) << 14) + ((kh) << 13); int go_ = (kt) * 64 + (kh) * 32; \
    gload16(sB0 + go_, dB + off_); gload16(sB1 + go_, dB + off_ + 512); }
#define RDA03(buf, kh) { const u16* a_ = rA + ((buf) << 14) + ((kh) << 13); \
    const u16* b_ = rB + ((buf) << 14) + ((kh) << 13); \
    _Pragma("unroll") for (int m_ = 0; m_ < 4; m_++) af[m_] = *(const bf16x8*)(a_ + m_ * 512); \
    _Pragma("unroll") for (int n_ = 0; n_ < 4; n_++) bfr[n_] = *(const bf16x8*)(b_ + n_ * 512); }
#define RDA47(buf, kh) { const u16* a_ = rA + ((buf) << 14) + ((kh) << 13); \
    _Pragma("unroll") for (int m_ = 4; m_ < 8; m_++) af[m_] = *(const bf16x8*)(a_ + m_ * 512); }
#define MM8(mlo) { _Pragma("unroll") for (int m_ = 0; m_ < 4; m_++) \
    { _Pragma("unroll") for (int n_ = 0; n_ < 4; n_++) \
      acc[(mlo) + m_][n_] = __builtin_amdgcn_mfma_f32_16x16x32_bf16(af[(mlo) + m_], bfr[n_], acc[(mlo) + m_][n_], 0, 0, 0); } }
#define PH_MID() __builtin_amdgcn_sched_barrier(0); __builtin_amdgcn_s_barrier(); \
    asm volatile("s_waitcnt lgkmcnt(0)" ::: "memory"); __builtin_amdgcn_sched_barrier(0); \
    __builtin_amdgcn_s_setprio(1)
#define PH_END() __builtin_amdgcn_s_setprio(0); __builtin_amdgcn_sched_barrier(0); \
    __builtin_amdgcn_s_barrier(); __builtin_amdgcn_sched_barrier(0)
#define PH_END_VM(n) __builtin_amdgcn_s_setprio(0); __builtin_amdgcn_sched_barrier(0); \
    asm volatile("s_waitcnt vmcnt(" #n ")" ::: "memory"); \
    __builtin_amdgcn_s_barrier(); __builtin_amdgcn_sched_barrier(0)

// ---------------- GEMM1 (8-phase, persistent): H = relu(gather(hbf) @ wiT^T) ----------------
__global__ __launch_bounds__(512, 1) void gemm1_8p(
    const u16* __restrict__ hbf, const u16* __restrict__ wiT, size_t wstride,
    const int* __restrict__ slot_token, const int* __restrict__ counts,
    const u16* __restrict__ zerobuf, u16* __restrict__ Hbuf,
    int p0, int nItems, const int* __restrict__ glist, const int* __restrict__ ngp)
{
    constexpr int KDIM = kD, NTn = kF / 256, NKT = KDIM / 64, NI = NKT / 2;
    int tid = threadIdx.x, w = tid >> 6, l = tid & 63;
    int wr = w >> 2, wc = w & 3;
    int fr = l & 15, fq = l >> 4;
    int r0 = w * 32 + (l >> 2), r1 = r0 + 16;
    int clog = (l & 3) ^ ((l >> 3) & 3);
    int sw = (fr >> 1) & 3;

    extern __shared__ __align__(16) u16 lds[];
    u16* Ap = lds;
    u16* Bp = lds + 32768;
    int* slots = (int*)(lds + 65536);
    u16* dA = Ap + w * 1024;
    u16* dB = Bp + w * 1024;
    const u16* rA = Ap + (wr * 128 + fr) * 32 + ((fq ^ sw) << 3);
    const u16* rB = Bp + (wc * 64 + fr) * 32 + ((fq ^ sw) << 3);
    int nblk = gridDim.x;
    int nI = glist ? (*ngp) * NTn : nItems;

    #pragma unroll 1
    for (int i = blockIdx.x; i < nI; i += nblk) {
        int pem, mt, nt, pl;
        if (glist) {
            int gpk = glist[i / NTn];
            nt = i % NTn;
            pem = gpk >> 1; mt = gpk & 1; pl = pem;
        } else {
            nt = i % NTn;
            int g = i / NTn;
            mt = g & 1; pem = p0 + (g >> 1); pl = pem - p0;
        }
        int e = pem >> 3, b = pem & 7;
        int pair = b * kE + e;
        if (!glist) {
            int cnt = counts[pair];
            if (mt * 256 >= cnt) continue;
        }

        if (tid < 256) slots[tid] = slot_token[pair * kC + mt * 256 + tid];
        __syncthreads();

        int sl0 = slots[r0], sl1 = slots[r1];
        const u16* sA0 = (sl0 >= 0) ? hbf + (size_t)(b * kS + sl0) * kD + clog * 8 : zerobuf + clog * 8;
        const u16* sA1 = (sl1 >= 0) ? hbf + (size_t)(b * kS + sl1) * kD + clog * 8 : zerobuf + clog * 8;
        const u16* wbase = wiT + (size_t)e * wstride;
        const u16* sB0 = wbase + (size_t)(nt * 256 + r0) * KDIM + clog * 8;
        const u16* sB1 = wbase + (size_t)(nt * 256 + r1) * KDIM + clog * 8;

        f32x4 acc[8][4];
        #pragma unroll
        for (int m = 0; m < 8; m++)
            #pragma unroll
            for (int n = 0; n < 4; n++) acc[m][n] = (f32x4){0.f, 0.f, 0.f, 0.f};
        bf16x8 af[8], bfr[4];

        SA8(0, 0) SB8(0, 0) SA8(0, 1) SB8(0, 1) SA8(1, 0) SB8(1, 0) SA8(1, 1)
        asm volatile("s_waitcnt vmcnt(6)" ::: "memory");
        __builtin_amdgcn_s_barrier();
        __builtin_amdgcn_sched_barrier(0);

        #pragma unroll 1
        for (int i2 = 0; i2 < NI - 1; ++i2) {
            int kt0 = 2 * i2;
            RDA03(0, 0) SB8(kt0 + 1, 1) PH_MID(); MM8(0) PH_END();           // P1
            RDA47(0, 0) SA8(kt0 + 2, 0) PH_MID(); MM8(4) PH_END();           // P2
            RDA03(0, 1) SB8(kt0 + 2, 0) PH_MID(); MM8(0) PH_END();           // P3
            RDA47(0, 1) SA8(kt0 + 2, 1) PH_MID(); MM8(4) PH_END_VM(6);       // P4
            RDA03(1, 0) SB8(kt0 + 2, 1) PH_MID(); MM8(0) PH_END();           // P5
            RDA47(1, 0) SA8(kt0 + 3, 0) PH_MID(); MM8(4) PH_END();           // P6
            RDA03(1, 1) SB8(kt0 + 3, 0) PH_MID(); MM8(0) PH_END();           // P7
            RDA47(1, 1) SA8(kt0 + 3, 1) PH_MID(); MM8(4) PH_END_VM(6);       // P8
        }
        RDA03(0, 0) SB8(NKT - 1, 1) PH_MID(); MM8(0) PH_END();
        RDA47(0, 0) PH_MID(); MM8(4) PH_END();
        RDA03(0, 1) PH_MID(); MM8(0) PH_END();
        RDA47(0, 1) PH_MID(); MM8(4) PH_END_VM(0);
        RDA03(1, 0) PH_MID(); MM8(0) PH_END();
        RDA47(1, 0) PH_MID(); MM8(4) PH_END();
        RDA03(1, 1) PH_MID(); MM8(0) PH_END();
        RDA47(1, 1) PH_MID(); MM8(4) __builtin_amdgcn_s_setprio(0); __builtin_amdgcn_sched_barrier(0);

        size_t hbase = (size_t)pl * kC * kF;
        int rbase = mt * 256 + wr * 128, c0 = nt * 256 + wc * 64;
        #pragma unroll
        for (int m = 0; m < 8; m++) {
            #pragma unroll
            for (int j = 0; j < 4; j++) {
                int row = rbase + m * 16 + fq * 4 + j;
                size_t rb = hbase + (size_t)row * kF;
                #pragma unroll
                for (int n = 0; n < 4; n++)
                    Hbuf[rb + c0 + n * 16 + fr] = f2bf(fmaxf(acc[m][n][j], 0.f));
            }
        }
        __syncthreads();   // protect slots[] before next item
    }
}

// ---------------- GEMM2 (8-phase, persistent): out = (H @ woT^T) * max_prob ----------------
__global__ __launch_bounds__(512, 1) void gemm2_8p(
    const u16* __restrict__ Hbuf, const u16* __restrict__ woT, size_t wstride,
    const int* __restrict__ slot_token, const int* __restrict__ counts,
    const float* __restrict__ maxprob, float* __restrict__ outp,
    int p0, int nItems, const int* __restrict__ glist, const int* __restrict__ ngp)
{
    constexpr int KDIM = kF, NTn = kD / 256, NKT = KDIM / 64, NI = NKT / 2;
    int tid = threadIdx.x, w = tid >> 6, l = tid & 63;
    int wr = w >> 2, wc = w & 3;
    int fr = l & 15, fq = l >> 4;
    int r0 = w * 32 + (l >> 2), r1 = r0 + 16;
    int clog = (l & 3) ^ ((l >> 3) & 3);
    int sw = (fr >> 1) & 3;

    extern __shared__ __align__(16) u16 lds[];
    u16* Ap = lds;
    u16* Bp = lds + 32768;
    int* slots = (int*)(lds + 65536);
    u16* dA = Ap + w * 1024;
    u16* dB = Bp + w * 1024;
    const u16* rA = Ap + (wr * 128 + fr) * 32 + ((fq ^ sw) << 3);
    const u16* rB = Bp + (wc * 64 + fr) * 32 + ((fq ^ sw) << 3);
    int nblk = gridDim.x;
    int nI = glist ? (*ngp) * NTn : nItems;

    #pragma unroll 1
    for (int i = blockIdx.x; i < nI; i += nblk) {
        int pem, mt, nt, pl;
        if (glist) {
            int gpk = glist[i / NTn];
            nt = i % NTn;
            pem = gpk >> 1; mt = gpk & 1; pl = pem;
        } else {
            nt = i % NTn;
            int g = i / NTn;
            mt = g & 1; pem = p0 + (g >> 1); pl = pem - p0;
        }
        int e = pem >> 3, b = pem & 7;
        int pair = b * kE + e;
        if (!glist) {
            int cnt = counts[pair];
            if (mt * 256 >= cnt) continue;
        }

        if (tid < 256) slots[tid] = slot_token[pair * kC + mt * 256 + tid];
        __syncthreads();

        const u16* sA0 = Hbuf + ((size_t)pl * kC + mt * 256 + r0) * kF + clog * 8;
        const u16* sA1 = Hbuf + ((size_t)pl * kC + mt * 256 + r1) * kF + clog * 8;
        const u16* wbase = woT + (size_t)e * wstride;
        const u16* sB0 = wbase + (size_t)(nt * 256 + r0) * KDIM + clog * 8;
        const u16* sB1 = wbase + (size_t)(nt * 256 + r1) * KDIM + clog * 8;

        f32x4 acc[8][4];
        #pragma unroll
        for (int m = 0; m < 8; m++)
            #pragma unroll
            for (int n = 0; n < 4; n++) acc[m][n] = (f32x4){0.f, 0.f, 0.f, 0.f};
        bf16x8 af[8], bfr[4];

        SA8(0, 0) SB8(0, 0) SA8(0, 1) SB8(0, 1) SA8(1, 0) SB8(1, 0) SA8(1, 1)
        asm volatile("s_waitcnt vmcnt(6)" ::: "memory");
        __builtin_amdgcn_s_barrier();
        __builtin_amdgcn_sched_barrier(0);

        #pragma unroll 1
        for (int i2 = 0; i2 < NI - 1; ++i2) {
            int kt0 = 2 * i2;
            RDA03(0, 0) SB8(kt0 + 1, 1) PH_MID(); MM8(0) PH_END();
            RDA47(0, 0) SA8(kt0 + 2, 0) PH_MID(); MM8(4) PH_END();
            RDA03(0, 1) SB8(kt0 + 2, 0) PH_MID(); MM8(0) PH_END();
            RDA47(0, 1) SA8(kt0 + 2, 1) PH_MID(); MM8(4) PH_END_VM(6);
            RDA03(1, 0) SB8(kt0 + 2, 1) PH_MID(); MM8(0) PH_END();
            RDA47(1, 0) SA8(kt0 + 3, 0) PH_MID(); MM8(4) PH_END();
            RDA03(1, 1) SB8(kt0 + 3, 0) PH_MID(); MM8(0) PH_END();
            RDA47(1, 1) SA8(kt0 + 3, 1) PH_MID(); MM8(4) PH_END_VM(6);
        }
        RDA03(0, 0) SB8(NKT - 1, 1) PH_MID(); MM8(0) PH_END();
        RDA47(0, 0) PH_MID(); MM8(4) PH_END();
        RDA03(0, 1) PH_MID(); MM8(0) PH_END();
        RDA47(0, 1) PH_MID(); MM8(4) PH_END_VM(0);
        RDA03(1, 0) PH_MID(); MM8(0) PH_END();
        RDA47(1, 0) PH_MID(); MM8(4) PH_END();
        RDA03(1, 1) PH_MID(); MM8(0) PH_END();
        RDA47(1, 1) PH_MID(); MM8(4) __builtin_amdgcn_s_setprio(0); __builtin_amdgcn_sched_barrier(0);

        int c0 = nt * 256 + wc * 64;
        #pragma unroll
        for (int m = 0; m < 8; m++) {
            #pragma unroll
            for (int j = 0; j < 4; j++) {
                int rl = wr * 128 + m * 16 + fq * 4 + j;
                int s = slots[rl];
                if (s >= 0) {
                    float p = maxprob[b * kS + s];
                    size_t ob = (size_t)(b * kS + s) * kD;
                    #pragma unroll
                    for (int n = 0; n < 4; n++)
                        outp[ob + c0 + n * 16 + fr] = acc[m][n][j] * p;
                }
            }
        }
        __syncthreads();   // protect slots[] before next item
    }
}

#undef SA8
#undef SB8
#undef RDA03
#undef RDA47
#undef MM8
#undef PH_MID
#undef PH_END
#undef PH_END_VM

// ---------------- naive fp32 fallback (proven) ----------------
__global__ __launch_bounds__(256) void ngemm1_k(
    const float* __restrict__ hidden, const float* __restrict__ wi,
    const int* __restrict__ slot_token, const int* __restrict__ counts,
    float* __restrict__ H, int pair)
{
    int b = pair >> 3, e = pair & 7;
    int cnt = counts[pair];
    int c0 = blockIdx.y * 64, f0 = blockIdx.x * 64;
    if (c0 >= cnt) return;
    __shared__ float As[64][17];
    __shared__ float Bs[16][65];
    __shared__ int slots[64];
    int tx = threadIdx.x, ty = threadIdx.y;
    int tid = ty * 16 + tx;
    if (tid < 64) slots[tid] = slot_token[pair * kC + c0 + tid];
    __syncthreads();
    float acc[4][4];
    #pragma unroll
    for (int i = 0; i < 4; i++)
        #pragma unroll
        for (int j = 0; j < 4; j++) acc[i][j] = 0.f;
    int ar = tid >> 2, ak = (tid & 3) * 4;
    int bd = tid >> 4, bf = (tid & 15) * 4;
    const float* wie = wi + (size_t)e * kD * kF;
    for (int k0 = 0; k0 < kD; k0 += 16) {
        int sl = slots[ar];
        if (sl >= 0) {
            float4 v = *(const float4*)(hidden + (size_t)(b * kS + sl) * kD + k0 + ak);
            As[ar][ak] = v.x; As[ar][ak + 1] = v.y; As[ar][ak + 2] = v.z; As[ar][ak + 3] = v.w;
        } else {
            As[ar][ak] = 0.f; As[ar][ak + 1] = 0.f; As[ar][ak + 2] = 0.f; As[ar][ak + 3] = 0.f;
        }
        float4 wv = *(const float4*)(wie + (size_t)(k0 + bd) * kF + f0 + bf);
        Bs[bd][bf] = wv.x; Bs[bd][bf + 1] = wv.y; Bs[bd][bf + 2] = wv.z; Bs[bd][bf + 3] = wv.w;
        __syncthreads();
        #pragma unroll
        for (int kk = 0; kk < 16; kk++) {
            float a[4], bv[4];
            #pragma unroll
            for (int i = 0; i < 4; i++) a[i] = As[ty * 4 + i][kk];
            #pragma unroll
            for (int j = 0; j < 4; j++) bv[j] = Bs[kk][tx * 4 + j];
            #pragma unroll
            for (int i = 0; i < 4; i++)
                #pragma unroll
                for (int j = 0; j < 4; j++) acc[i][j] += a[i] * bv[j];
        }
        __syncthreads();
    }
    #pragma unroll
    for (int i = 0; i < 4; i++) {
        int row = c0 + ty * 4 + i;
        #pragma unroll
        for (int j = 0; j < 4; j++)
            H[(size_t)row * kF + f0 + tx * 4 + j] = fmaxf(acc[i][j], 0.f);
    }
}

__global__ __launch_bounds__(256) void ngemm2_k(
    const float* __restrict__ H, const float* __restrict__ wo,
    const int* __restrict__ slot_token, const int* __restrict__ counts,
    const float* __restrict__ maxprob, float* __restrict__ outp, int pair)
{
    int b = pair >> 3, e = pair & 7;
    int cnt = counts[pair];
    int c0 = blockIdx.y * 64, d0 = blockIdx.x * 64;
    if (c0 >= cnt) return;
    __shared__ float As[64][17];
    __shared__ float Bs[16][65];
    __shared__ int slots[64];
    int tx = threadIdx.x, ty = threadIdx.y;
    int tid = ty * 16 + tx;
    if (tid < 64) slots[tid] = slot_token[pair * kC + c0 + tid];
    __syncthreads();
    float acc[4][4];
    #pragma unroll
    for (int i = 0; i < 4; i++)
        #pragma unroll
        for (int j = 0; j < 4; j++) acc[i][j] = 0.f;
    int ar = tid >> 2, ak = (tid & 3) * 4;
    int bd = tid >> 4, bf = (tid & 15) * 4;
    const float* woe = wo + (size_t)e * kF * kD;
    for (int k0 = 0; k0 < kF; k0 += 16) {
        float4 v = *(const float4*)(H + (size_t)(c0 + ar) * kF + k0 + ak);
        As[ar][ak] = v.x; As[ar][ak + 1] = v.y; As[ar][ak + 2] = v.z; As[ar][ak + 3] = v.w;
        float4 wv = *(const float4*)(woe + (size_t)(k0 + bd) * kD + d0 + bf);
        Bs[bd][bf] = wv.x; Bs[bd][bf + 1] = wv.y; Bs[bd][bf + 2] = wv.z; Bs[bd][bf + 3] = wv.w;
        __syncthreads();
        #pragma unroll
        for (int kk = 0; kk < 16; kk++) {
            float a[4], bv[4];
            #pragma unroll
            for (int i = 0; i < 4; i++) a[i] = As[ty * 4 + i][kk];
            #pragma unroll
            for (int j = 0; j < 4; j++) bv[j] = Bs[kk][tx * 4 + j];
            #pragma unroll
            for (int i = 0; i < 4; i++)
                #pragma unroll
                for (int j = 0; j < 4; j++) acc[i][j] += a[i] * bv[j];
        }
        __syncthreads();
    }
    #pragma unroll
    for (int i = 0; i < 4; i++) {
        int s = slots[ty * 4 + i];
        if (s >= 0) {
            float p = maxprob[b * kS + s];
            size_t ob = (size_t)(b * kS + s) * kD;
            #pragma unroll
            for (int j = 0; j < 4; j++)
                outp[ob + d0 + tx * 4 + j] = acc[i][j] * p;
        }
    }
}

extern "C" void kernel_launch(void* const* d_in, const int* in_sizes, int n_in,
                              void* d_out, int out_size, void* d_ws, size_t ws_size,
                              hipStream_t stream)
{
    const float* hidden = (const float*)d_in[0];
    const float* rw     = (const float*)d_in[1];
    const float* wi     = (const float*)d_in[2];
    const float* wo     = (const float*)d_in[3];
    float* outp   = (float*)d_out;
    float* logits = outp + (size_t)kB * kS * kD;
    float* expidx = logits + (size_t)kB * kS * kE;

    char* ws = (char*)d_ws;
    size_t off = 0;
    auto alloc = [&](size_t bytes) -> char* {
        char* p = ws + off; off += (bytes + 255) & ~(size_t)255; return p;
    };
    int*   slot_token = (int*)  alloc((size_t)kB * kE * kC * 4);
    int*   counts     = (int*)  alloc((size_t)kB * kE * 4);
    int*   expert_id  = (int*)  alloc((size_t)kB * kS * 4);
    float* maxprob    = (float*)alloc((size_t)kB * kS * 4);
    int*   glist      = (int*)  alloc(256 * 4);
    int*   ngp        = (int*)  alloc(256);
    size_t small_off = off;

    const size_t wsz   = (size_t)kD * kF * 2;       // 8 MiB per expert, bf16
    const size_t hsz   = (size_t)kC * kF * 2;       // 4 MiB per pair, bf16
    const size_t hbfsz = (size_t)kB * kS * kD * 2;  // 32 MiB bf16 hidden image

    hipFuncSetAttribute(reinterpret_cast<const void*>(gemm1_8p),
                        hipFuncAttributeMaxDynamicSharedMemorySize, kSmemBytes);
    hipFuncSetAttribute(reinterpret_cast<const void*>(gemm2_8p),
                        hipFuncAttributeMaxDynamicSharedMemorySize, kSmemBytes);

    bool tierA = ws_size >= small_off + 2 * kE * wsz + hbfsz + 4096 + 4 * hsz;
    bool tierB = !tierA && ws_size >= small_off + 2 * wsz + hbfsz + 4096 + hsz;

    if (tierA) {
        u16* wiT = (u16*)alloc(kE * wsz);   // 64 MiB
        u16* woT = (u16*)alloc(kE * wsz);   // 64 MiB
        u16* hbf = (u16*)alloc(hbfsz);      // 32 MiB
        u16* zerobuf = (u16*)alloc(4096);
        int Gb = (int)((ws_size - off) / hsz);
        if (Gb > kB * kE) Gb = kB * kE;
        if (Gb < 1) Gb = 1;
        u16* Hbuf = (u16*)alloc((size_t)Gb * hsz);

        init_k<<<2048, 256, 0, stream>>>((uint4*)outp, (uint4*)zerobuf);
        router_k<<<kB * kS / 4, 256, 0, stream>>>(hidden, rw, logits, expert_id, maxprob, hbf);
        scan_k<<<kB, 64, 0, stream>>>(expert_id, slot_token, counts, expidx);
        build_k<<<1, 64, 0, stream>>>(counts, glist, ngp);
        transpose_v<<<dim3(kF / 64, kD / 64, kE), 256, 0, stream>>>(wi, wiT, kD, kF);
        transpose_v<<<dim3(kD / 64, kF / 64, kE), 256, 0, stream>>>(wo, woT, kF, kD);

        if (Gb == kB * kE) {
            gemm1_8p<<<256, 512, kSmemBytes, stream>>>(
                hbf, wiT, (size_t)kD * kF, slot_token, counts, zerobuf, Hbuf, 0, 0, glist, ngp);
            gemm2_8p<<<256, 512, kSmemBytes, stream>>>(
                Hbuf, woT, (size_t)kD * kF, slot_token, counts, maxprob, outp, 0, 0, glist, ngp);
        } else {
            for (int p0 = 0; p0 < kB * kE; p0 += Gb) {
                int g = kB * kE - p0 < Gb ? kB * kE - p0 : Gb;
                gemm1_8p<<<g * 2 * (kF / 256), 512, kSmemBytes, stream>>>(
                    hbf, wiT, (size_t)kD * kF, slot_token, counts, zerobuf, Hbuf,
                    p0, g * 2 * (kF / 256), nullptr, nullptr);
                gemm2_8p<<<g * 2 * (kD / 256), 512, kSmemBytes, stream>>>(
                    Hbuf, woT, (size_t)kD * kF, slot_token, counts, maxprob, outp,
                    p0, g * 2 * (kD / 256), nullptr, nullptr);
            }
        }
    } else if (tierB) {
        u16* wiT = (u16*)alloc(wsz);
        u16* woT = (u16*)alloc(wsz);
        u16* hbf = (u16*)alloc(hbfsz);
        u16* zerobuf = (u16*)alloc(4096);
        int Gb = (int)((ws_size - off) / hsz);
        if (Gb > kB) Gb = kB;
        if (Gb < 1) Gb = 1;
        u16* Hbuf = (u16*)alloc((size_t)Gb * hsz);

        init_k<<<2048, 256, 0, stream>>>((uint4*)outp, (uint4*)zerobuf);
        router_k<<<kB * kS / 4, 256, 0, stream>>>(hidden, rw, logits, expert_id, maxprob, hbf);
        scan_k<<<kB, 64, 0, stream>>>(expert_id, slot_token, counts, expidx);
        for (int e = 0; e < kE; e++) {
            transpose_v<<<dim3(kF / 64, kD / 64, 1), 256, 0, stream>>>(
                wi + (size_t)e * kD * kF, wiT, kD, kF);
            transpose_v<<<dim3(kD / 64, kF / 64, 1), 256, 0, stream>>>(
                wo + (size_t)e * kD * kF, woT, kF, kD);
            for (int b0 = 0; b0 < kB; b0 += Gb) {
                int g = kB - b0 < Gb ? kB - b0 : Gb;
                int p0 = e * 8 + b0;
                gemm1_8p<<<g * 2 * (kF / 256), 512, kSmemBytes, stream>>>(
                    hbf, wiT, 0, slot_token, counts, zerobuf, Hbuf,
                    p0, g * 2 * (kF / 256), nullptr, nullptr);
                gemm2_8p<<<g * 2 * (kD / 256), 512, kSmemBytes, stream>>>(
                    Hbuf, woT, 0, slot_token, counts, maxprob, outp,
                    p0, g * 2 * (kD / 256), nullptr, nullptr);
            }
        }
    } else {
        float* H = (float*)alloc((size_t)kC * kF * 4);
        init_k<<<2048, 256, 0, stream>>>((uint4*)outp, nullptr);
        router_k<<<kB * kS / 4, 256, 0, stream>>>(hidden, rw, logits, expert_id, maxprob, nullptr);
        scan_k<<<kB, 64, 0, stream>>>(expert_id, slot_token, counts, expidx);
        for (int pair = 0; pair < kB * kE; pair++) {
            ngemm1_k<<<dim3(kF / 64, kC / 64), dim3(16, 16), 0, stream>>>(
                hidden, wi, slot_token, counts, H, pair);
            ngemm2_k<<<dim3(kD / 64, kC / 64), dim3(16, 16), 0, stream>>>(
                H, wo, slot_token, counts, maxprob, outp, pair);
        }
    }
}